// Round 19
// baseline (351.484 us; speedup 1.0000x reference)
//
#include <hip/hip_runtime.h>
#include <stdint.h>

// Problem constants
#define BATCH 16
#define CIN   1024
#define HWSZ  1024
#define NPOS  16384
#define DCODE 1024
#define KCB   2048

// d_out FLOAT32: [0,16777216) quant (B,D,H,W); [16777216] diff; [16777217,+16384) indices
#define OUT_QUANT 0
#define OUT_DIFF  16777216
#define OUT_IDX   16777217

// ws layout (bytes)
#define OFF_PACKED 0u            // 16384 u64 = 128 KB
#define OFF_CNORM  131072u       // 2048 f32
#define OFF_DIFF   139264u       // 1 double
#define OFF_WH     262144u       // [d][c] f16, 2 MB
#define OFF_WL     2359296u
#define OFF_CBH    4456448u      // [k][d] f16, 4 MB
#define OFF_CBL    8650752u
#define OFF_DYN    12845056u
// fast dyn: xh 32M | xl 32M | xph 32M | xpl 32M | xq 16M | cq 2M | bestd 128K
// dq u16 [16384][2048] ALIASES d_out quant region; screen->refine->gather chain.

typedef _Float16 f16x8 __attribute__((ext_vector_type(8)));
typedef float f32x4 __attribute__((ext_vector_type(4)));
typedef int i32x4 __attribute__((ext_vector_type(4)));
union H4 { _Float16 h[4]; uint2 u; };
union H8 { _Float16 h[8]; uint4 u; };
union QU { uint4 u; uint16_t v[8]; };
union B16 { char c[16]; uint4 u; };

__device__ __forceinline__ void gl_lds16(const void* g, void* l) {
  __builtin_amdgcn_global_load_lds(
      (const __attribute__((address_space(1))) uint32_t*)g,
      (__attribute__((address_space(3))) uint32_t*)l, 16, 0, 0);
}

__device__ __forceinline__ char q8(float v, float s) {
  int qi = (int)rintf(v * s);
  return (char)(qi > 127 ? 127 : (qi < -127 ? -127 : qi));
}

__global__ void k_init(unsigned long long* __restrict__ packed, double* __restrict__ diffsum) {
  int i = blockIdx.x * 256 + threadIdx.x;
  if (i < NPOS) packed[i] = 0xFFFFFFFFFFFFFFFFull;
  if (i == 0) *diffsum = 0.0;
}

__global__ __launch_bounds__(256) void k_prep_w(const float* __restrict__ w,
                                                _Float16* __restrict__ wh, _Float16* __restrict__ wl) {
  const int d = blockIdx.x;
  const int c = threadIdx.x * 4;
  float4 v = *(const float4*)&w[(size_t)d * CIN + c];
  H4 hh, ll;
  float vv[4] = {v.x, v.y, v.z, v.w};
  #pragma unroll
  for (int i = 0; i < 4; ++i) {
    _Float16 h = (_Float16)vv[i];
    hh.h[i] = h;
    ll.h[i] = (_Float16)(vv[i] - (float)h);
  }
  *(uint2*)&wh[(size_t)d * CIN + c] = hh.u;
  *(uint2*)&wl[(size_t)d * CIN + c] = ll.u;
}

// cbh/cbl [k][d] (+ optional cq i8 scale 20) from cb [d][k]
__global__ __launch_bounds__(256) void k_prep_cb(const float* __restrict__ cb,
                                                 _Float16* __restrict__ cbh, _Float16* __restrict__ cbl,
                                                 char* __restrict__ cq) {
  __shared__ float ts[64][65];
  const int t = threadIdx.x;
  const int k0 = blockIdx.x * 64, d0 = blockIdx.y * 64;
  #pragma unroll
  for (int i = 0; i < 4; ++i) {
    const int r = i * 16 + (t >> 4);
    float4 v = *(const float4*)&cb[(size_t)(d0 + r) * KCB + k0 + (t & 15) * 4];
    ts[r][(t & 15) * 4 + 0] = v.x; ts[r][(t & 15) * 4 + 1] = v.y;
    ts[r][(t & 15) * 4 + 2] = v.z; ts[r][(t & 15) * 4 + 3] = v.w;
  }
  __syncthreads();
  const int j = t >> 2;
  const int q = t & 3;
  H8 hh[2], ll[2];
  B16 qb;
  #pragma unroll
  for (int e = 0; e < 16; ++e) {
    float xv = ts[q * 16 + e][j];
    _Float16 h = (_Float16)xv;
    hh[e >> 3].h[e & 7] = h;
    ll[e >> 3].h[e & 7] = (_Float16)(xv - (float)h);
    qb.c[e] = q8(xv, 20.f);
  }
  size_t o = (size_t)(k0 + j) * DCODE + d0 + q * 16;
  *(uint4*)&cbh[o] = hh[0].u; *(uint4*)&cbh[o + 8] = hh[1].u;
  *(uint4*)&cbl[o] = ll[0].u; *(uint4*)&cbl[o + 8] = ll[1].u;
  if (cq) *(uint4*)&cq[o] = qb.u;
}

// xh/xl [nloc][c] from x[b][c][hw]
__global__ __launch_bounds__(256) void k_prep_x(const float* __restrict__ x,
                                                _Float16* __restrict__ xh, _Float16* __restrict__ xl,
                                                int n_base) {
  __shared__ float ts[64][65];
  const int t = threadIdx.x;
  const int nt0 = blockIdx.x * 64;
  const int c0 = blockIdx.y * 64;
  const int ng = n_base + nt0;
  const int b = ng >> 10, hw0 = ng & 1023;
  #pragma unroll
  for (int i = 0; i < 4; ++i) {
    const int r = i * 16 + (t >> 4);
    float4 v = *(const float4*)&x[((size_t)b * CIN + c0 + r) * HWSZ + hw0 + (t & 15) * 4];
    ts[r][(t & 15) * 4 + 0] = v.x; ts[r][(t & 15) * 4 + 1] = v.y;
    ts[r][(t & 15) * 4 + 2] = v.z; ts[r][(t & 15) * 4 + 3] = v.w;
  }
  __syncthreads();
  const int j = t >> 2;
  const int q = t & 3;
  H8 hh[2], ll[2];
  #pragma unroll
  for (int e = 0; e < 16; ++e) {
    float xv = ts[q * 16 + e][j];
    _Float16 h = (_Float16)xv;
    hh[e >> 3].h[e & 7] = h;
    ll[e >> 3].h[e & 7] = (_Float16)(xv - (float)h);
  }
  size_t o = (size_t)(nt0 + j) * CIN + c0 + q * 16;
  *(uint4*)&xh[o] = hh[0].u; *(uint4*)&xh[o + 8] = hh[1].u;
  *(uint4*)&xl[o] = ll[0].u; *(uint4*)&xl[o + 8] = ll[1].u;
}

__global__ __launch_bounds__(256) void k_cnorm2(const _Float16* __restrict__ cbh,
                                                const _Float16* __restrict__ cbl,
                                                float* __restrict__ cnorm) {
  __shared__ double rd[256];
  const int k = blockIdx.x;
  const int t = threadIdx.x;
  H4 hh, ll;
  hh.u = *(const uint2*)&cbh[(size_t)k * DCODE + t * 4];
  ll.u = *(const uint2*)&cbl[(size_t)k * DCODE + t * 4];
  double s = 0.0;
  #pragma unroll
  for (int i = 0; i < 4; ++i) {
    float v = (float)hh.h[i] + (float)ll.h[i];
    s += (double)v * v;
  }
  rd[t] = s;
  __syncthreads();
  for (int st = 128; st > 0; st >>= 1) {
    if (t < st) rd[t] += rd[t + st];
    __syncthreads();
  }
  if (t == 0) cnorm[k] = (float)rd[0];
}

// ---- Unified f16 3-product 256x256 BK=64 GEMM (r8/r15 proven schedule) ----
// EPI 0: bias + hi/lo plane stores (swizzled repack) + optional xq i8 (scale 20).
// EPI 1: argmin -> packed (fallback).
template <int EPI, int NKTT>
__global__ __launch_bounds__(512, 2) void k_gemm_u(
    const _Float16* __restrict__ aH, const _Float16* __restrict__ aL,
    const _Float16* __restrict__ bH, const _Float16* __restrict__ bL,
    const float* __restrict__ bias,
    _Float16* __restrict__ oH, _Float16* __restrict__ oL,
    const float* __restrict__ cnorm, unsigned long long* __restrict__ packed,
    char* __restrict__ xqout, int n_base) {
  __shared__ __align__(16) _Float16 smem[65536];  // 128 KB
  const int tid = threadIdx.x;
  const int lane = tid & 63, wid = tid >> 6;
  const int wm = wid >> 2, wn = wid & 3;
  const int m0 = blockIdx.x * 256;
  const int n0 = blockIdx.y * 256;
  const int kg = lane >> 4;
  const int l7 = lane & 7;

  const int srow = lane >> 3;
  const int sg = l7 ^ srow;
  size_t srcA[4], srcB[4];
  int sdst[4];
  #pragma unroll
  for (int i = 0; i < 4; ++i) {
    const int r = i * 64 + wid * 8 + srow;
    srcA[i] = (size_t)(m0 + r) * 1024 + sg * 8;
    srcB[i] = (size_t)(n0 + r) * 1024 + sg * 8;
    sdst[i] = i * 4096 + wid * 512;
  }
  const int xrd[2] = {(kg ^ l7) * 8, ((4 + kg) ^ l7) * 8};
  int arow[8], brow[4];
  #pragma unroll
  for (int fi = 0; fi < 8; ++fi) arow[fi] = (wm * 128 + fi * 16 + (lane & 15)) * 64;
  #pragma unroll
  for (int fj = 0; fj < 4; ++fj) brow[fj] = 16384 + (wn * 64 + fj * 16 + (lane & 15)) * 64;

  auto stage = [&](int kt, int part) {
    const int tp = kt >> 4;
    const int dbase = (kt & 15) * 64;
    const int buf = (kt & 1) << 15;
    if (part == 0) {
      const _Float16* pA = (tp == 2 ? aL : aH);
      #pragma unroll
      for (int i = 0; i < 4; ++i) gl_lds16(pA + srcA[i] + dbase, smem + buf + sdst[i]);
    } else {
      const _Float16* pB = (tp == 1 ? bL : bH);
      #pragma unroll
      for (int i = 0; i < 4; ++i) gl_lds16(pB + srcB[i] + dbase, smem + buf + 16384 + sdst[i]);
    }
  };

  f32x4 acc[8][4];
  #pragma unroll
  for (int i = 0; i < 8; ++i)
    #pragma unroll
    for (int j = 0; j < 4; ++j) acc[i][j] = (f32x4){0.f, 0.f, 0.f, 0.f};

  stage(0, 0); stage(0, 1);
  asm volatile("s_waitcnt vmcnt(0)" ::: "memory");
  __builtin_amdgcn_s_barrier();
  __builtin_amdgcn_sched_barrier(0);

  for (int kt = 0; kt < NKTT; ++kt) {
    const int buf = (kt & 1) << 15;
    f16x8 bfr[4][2];
    #pragma unroll
    for (int fj = 0; fj < 4; ++fj)
      #pragma unroll
      for (int ks = 0; ks < 2; ++ks)
        bfr[fj][ks] = *(const f16x8*)&smem[buf + brow[fj] + xrd[ks]];
    #pragma unroll
    for (int q = 0; q < 4; ++q) {
      f16x8 afr[2][2];
      #pragma unroll
      for (int f2 = 0; f2 < 2; ++f2)
        #pragma unroll
        for (int ks = 0; ks < 2; ++ks)
          afr[f2][ks] = *(const f16x8*)&smem[buf + arow[q * 2 + f2] + xrd[ks]];
      if (kt < NKTT - 1) {
        if (q == 0) stage(kt + 1, 0);
        else if (q == 1) stage(kt + 1, 1);
      }
      __builtin_amdgcn_s_setprio(1);
      #pragma unroll
      for (int f2 = 0; f2 < 2; ++f2)
        #pragma unroll
        for (int fj = 0; fj < 4; ++fj)
          #pragma unroll
          for (int ks = 0; ks < 2; ++ks)
            acc[q * 2 + f2][fj] = __builtin_amdgcn_mfma_f32_16x16x32_f16(
                afr[f2][ks], bfr[fj][ks], acc[q * 2 + f2][fj], 0, 0, 0);
      __builtin_amdgcn_s_setprio(0);
      __builtin_amdgcn_sched_barrier(0);
    }
    asm volatile("s_waitcnt vmcnt(0)" ::: "memory");
    __builtin_amdgcn_s_barrier();
    __builtin_amdgcn_sched_barrier(0);
  }

  if (EPI == 1) {
    unsigned long long* su = (unsigned long long*)smem;
    float cn[4]; int kcol[4];
    #pragma unroll
    for (int fj = 0; fj < 4; ++fj) {
      kcol[fj] = n0 + wn * 64 + fj * 16 + (lane & 15);
      cn[fj] = cnorm[kcol[fj]];
    }
    #pragma unroll
    for (int fi = 0; fi < 8; ++fi) {
      #pragma unroll
      for (int r = 0; r < 4; ++r) {
        float best = 3.4e38f; int bk = 0;
        #pragma unroll
        for (int fj = 0; fj < 4; ++fj) {
          const float v = cn[fj] - 2.0f * acc[fi][fj][r];
          if (v < best) { best = v; bk = kcol[fj]; }
        }
        union { float f; uint32_t u; } cv; cv.f = best;
        uint32_t hi = cv.u ^ ((uint32_t)((int32_t)cv.u >> 31) | 0x80000000u);
        unsigned long long key = ((unsigned long long)hi << 32) | (uint32_t)bk;
        #pragma unroll
        for (int s = 1; s < 16; s <<= 1) {
          unsigned long long o = __shfl_xor(key, s, 64);
          if (o < key) key = o;
        }
        if ((lane & 15) == 0)
          su[wn * 256 + wm * 128 + fi * 16 + kg * 4 + r] = key;
      }
    }
    __syncthreads();
    if (tid < 256) {
      unsigned long long k = su[tid];
      #pragma unroll
      for (int w = 1; w < 4; ++w) {
        unsigned long long o = su[w * 256 + tid];
        if (o < k) k = o;
      }
      atomicMin(&packed[n_base + m0 + tid], k);
    }
  } else {
    // bias + hi/lo split, swizzled LDS repack; then optional xq i8
    float bi[4];
    #pragma unroll
    for (int fj = 0; fj < 4; ++fj) bi[fj] = bias[n0 + wn * 64 + fj * 16 + (lane & 15)];
    const int sw = kg << 4;
    #pragma unroll
    for (int pl = 0; pl < 2; ++pl) {
      #pragma unroll
      for (int fi = 0; fi < 8; ++fi)
        #pragma unroll
        for (int r = 0; r < 4; ++r) {
          const int pos_l = wm * 128 + fi * 16 + kg * 4 + r;
          #pragma unroll
          for (int fj = 0; fj < 4; ++fj) {
            const int d_l = wn * 64 + fj * 16 + (lane & 15);
            float v = acc[fi][fj][r] + bi[fj];
            _Float16 h = (_Float16)v;
            smem[pos_l * 256 + (d_l ^ sw)] = pl ? (_Float16)(v - (float)h) : h;
          }
        }
      __syncthreads();
      _Float16* dst = pl ? oL : oH;
      #pragma unroll
      for (int p = 0; p < 16; ++p) {
        const int row = p * 16 + (tid >> 5);
        const int lc = tid & 31;
        const int pc = lc ^ (((row >> 2) & 3) << 1);
        *(uint4*)&dst[(size_t)(m0 + row) * 1024 + n0 + lc * 8] = *(const uint4*)&smem[row * 256 + pc * 8];
      }
      __syncthreads();
    }
    if (xqout) {
      char* sm8 = (char*)smem;
      #pragma unroll
      for (int fi = 0; fi < 8; ++fi)
        #pragma unroll
        for (int r = 0; r < 4; ++r) {
          const int pos_l = wm * 128 + fi * 16 + kg * 4 + r;
          #pragma unroll
          for (int fj = 0; fj < 4; ++fj) {
            const int d_l = wn * 64 + fj * 16 + (lane & 15);
            sm8[pos_l * 256 + (d_l ^ sw)] = q8(acc[fi][fj][r] + bi[fj], 20.f);
          }
        }
      __syncthreads();
      #pragma unroll
      for (int p = 0; p < 8; ++p) {
        const int idx = p * 512 + tid;
        const int row = idx >> 4;
        const int ch = idx & 15;
        const int pch = ch ^ ((row >> 2) & 3);
        *(uint4*)&xqout[(size_t)(m0 + row) * 1024 + n0 + ch * 16] = *(const uint4*)&sm8[row * 256 + pch * 16];
      }
    }
  }
}

// ---- i8 screen GEMM (proven r15): dist quantized u16 -> dq ----
__global__ __launch_bounds__(512, 2) void k_screen_q(
    const char* __restrict__ xq, const char* __restrict__ cq,
    const float* __restrict__ cnorm, uint16_t* __restrict__ dqout) {
  __shared__ __align__(16) char smem[131072];
  const int tid = threadIdx.x;
  const int lane = tid & 63, wid = tid >> 6;
  const int wm = wid >> 2, wn = wid & 3;
  const int m0 = blockIdx.x * 256;
  const int n0 = blockIdx.y * 256;
  const int kg = lane >> 4;
  const int l7 = lane & 7;
  const int l15 = lane & 15;
  const int srow = lane >> 3;
  const int sg = l7 ^ srow;
  size_t srcA[4], srcB[4];
  int sdst[4];
  #pragma unroll
  for (int i = 0; i < 4; ++i) {
    const int r = i * 64 + wid * 8 + srow;
    srcA[i] = (size_t)(m0 + r) * 1024 + sg * 16;
    srcB[i] = (size_t)(n0 + r) * 1024 + sg * 16;
    sdst[i] = i * 8192 + wid * 1024;
  }
  const int xrd[2] = {(kg ^ l7) * 16, ((4 + kg) ^ l7) * 16};
  int arow[8], brow[4];
  #pragma unroll
  for (int fi = 0; fi < 8; ++fi) arow[fi] = (wm * 128 + fi * 16 + l15) * 128;
  #pragma unroll
  for (int fj = 0; fj < 4; ++fj) brow[fj] = 32768 + (wn * 64 + fj * 16 + l15) * 128;

  auto stage = [&](int kt, int part) {
    const int dbase = kt * 128;
    const int buf = (kt & 1) << 16;
    if (part == 0) {
      #pragma unroll
      for (int i = 0; i < 4; ++i) gl_lds16(xq + srcA[i] + dbase, smem + buf + sdst[i]);
    } else {
      #pragma unroll
      for (int i = 0; i < 4; ++i) gl_lds16(cq + srcB[i] + dbase, smem + buf + 32768 + sdst[i]);
    }
  };

  i32x4 acc[8][4];
  #pragma unroll
  for (int i = 0; i < 8; ++i)
    #pragma unroll
    for (int j = 0; j < 4; ++j) acc[i][j] = (i32x4){0, 0, 0, 0};

  stage(0, 0); stage(0, 1);
  asm volatile("s_waitcnt vmcnt(0)" ::: "memory");
  __builtin_amdgcn_s_barrier();
  __builtin_amdgcn_sched_barrier(0);

  for (int kt = 0; kt < 8; ++kt) {
    const int buf = (kt & 1) << 16;
    i32x4 bfr[4][2];
    #pragma unroll
    for (int fj = 0; fj < 4; ++fj)
      #pragma unroll
      for (int ks = 0; ks < 2; ++ks)
        bfr[fj][ks] = *(const i32x4*)&smem[buf + brow[fj] + xrd[ks]];
    #pragma unroll
    for (int q = 0; q < 4; ++q) {
      i32x4 afr[2][2];
      #pragma unroll
      for (int f2 = 0; f2 < 2; ++f2)
        #pragma unroll
        for (int ks = 0; ks < 2; ++ks)
          afr[f2][ks] = *(const i32x4*)&smem[buf + arow[q * 2 + f2] + xrd[ks]];
      if (kt < 7) {
        if (q == 0) stage(kt + 1, 0);
        else if (q == 1) stage(kt + 1, 1);
      }
      __builtin_amdgcn_s_setprio(1);
      #pragma unroll
      for (int f2 = 0; f2 < 2; ++f2)
        #pragma unroll
        for (int fj = 0; fj < 4; ++fj)
          #pragma unroll
          for (int ks = 0; ks < 2; ++ks)
            acc[q * 2 + f2][fj] = __builtin_amdgcn_mfma_i32_16x16x64_i8(
                afr[f2][ks], bfr[fj][ks], acc[q * 2 + f2][fj], 0, 0, 0);
      __builtin_amdgcn_s_setprio(0);
      __builtin_amdgcn_sched_barrier(0);
    }
    asm volatile("s_waitcnt vmcnt(0)" ::: "memory");
    __builtin_amdgcn_s_barrier();
    __builtin_amdgcn_sched_barrier(0);
  }

  uint16_t* sq = (uint16_t*)smem;
  float cn[4]; int kcolL[4];
  #pragma unroll
  for (int fj = 0; fj < 4; ++fj) {
    kcolL[fj] = wn * 64 + fj * 16 + l15;
    cn[fj] = cnorm[n0 + kcolL[fj]];
  }
  const int sw = kg << 4;
  #pragma unroll
  for (int fi = 0; fi < 8; ++fi)
    #pragma unroll
    for (int r = 0; r < 4; ++r) {
      const int pos_l = wm * 128 + fi * 16 + kg * 4 + r;
      #pragma unroll
      for (int fj = 0; fj < 4; ++fj) {
        float qf = (cn[fj] - 0.005f * (float)acc[fi][fj][r] - 512.f) * 16.f;
        uint32_t qq = qf <= 0.f ? 0u : (qf >= 65535.f ? 65535u : (uint32_t)qf);
        sq[pos_l * 256 + (kcolL[fj] ^ sw)] = (uint16_t)qq;
      }
    }
  __syncthreads();
  #pragma unroll
  for (int p = 0; p < 16; ++p) {
    const int row = p * 16 + (tid >> 5);
    const int lc = tid & 31;
    const int pc = lc ^ (((row >> 2) & 3) << 1);
    *(uint4*)&dqout[(size_t)(m0 + row) * 2048 + n0 + lc * 8] = *(const uint4*)&sq[row * 256 + pc * 8];
  }
}

// ---- refine: DETERMINISTIC candidate compaction (prefix scan, ascending k),
//      exact f64 recompute; best_d -> bestd[n] ----
__global__ __launch_bounds__(256) void k_refine(
    const uint16_t* __restrict__ dq,
    const _Float16* __restrict__ xph, const _Float16* __restrict__ xpl,
    const _Float16* __restrict__ cbh, const _Float16* __restrict__ cbl,
    unsigned long long* __restrict__ packed, double* __restrict__ bestd) {
  const int n = blockIdx.x;
  const int t = threadIdx.x;
  __shared__ float xpr[1024];
  __shared__ uint32_t smin[256];
  __shared__ double red[256];
  __shared__ int cand[256];
  __shared__ int scan[256];
  {
    H4 hh, ll;
    hh.u = *(const uint2*)&xph[(size_t)n * 1024 + t * 4];
    ll.u = *(const uint2*)&xpl[(size_t)n * 1024 + t * 4];
    #pragma unroll
    for (int i = 0; i < 4; ++i) xpr[t * 4 + i] = (float)hh.h[i] + (float)ll.h[i];
  }
  QU qv;
  qv.u = *(const uint4*)&dq[(size_t)n * 2048 + t * 8];
  uint32_t lmin = 0xFFFFFFFFu;
  #pragma unroll
  for (int j = 0; j < 8; ++j) lmin = (qv.v[j] < lmin) ? qv.v[j] : lmin;
  smin[t] = lmin;
  __syncthreads();
  for (int s = 128; s > 0; s >>= 1) {
    if (t < s && smin[t + s] < smin[t]) smin[t] = smin[t + s];
    __syncthreads();
  }
  uint32_t thr = smin[0] + 192;            // 12 dist units of i8-screen margin
  if (thr > 65535u) thr = 65535u;          // harden saturated-row corner
  // deterministic compaction: per-thread count -> inclusive scan -> ordered write
  int cnt = 0;
  #pragma unroll
  for (int j = 0; j < 8; ++j) cnt += (qv.v[j] <= thr) ? 1 : 0;
  scan[t] = cnt;
  __syncthreads();
  for (int off = 1; off < 256; off <<= 1) {
    int add = (t >= off) ? scan[t - off] : 0;
    __syncthreads();
    scan[t] += add;
    __syncthreads();
  }
  const int total = scan[255];
  int o = scan[t] - cnt;                   // exclusive prefix (ascending k order)
  #pragma unroll
  for (int j = 0; j < 8; ++j)
    if (qv.v[j] <= thr) {
      if (o < 256) cand[o] = t * 8 + j;
      ++o;
    }
  __syncthreads();
  int nc = total > 256 ? 256 : total;
  double best_d = 1e300; int best_k = 0x7FFFFFFF;
  for (int c = 0; c < nc; ++c) {
    const int k = cand[c];
    H4 ch, cl;
    ch.u = *(const uint2*)&cbh[(size_t)k * 1024 + t * 4];
    cl.u = *(const uint2*)&cbl[(size_t)k * 1024 + t * 4];
    double s = 0.0;
    #pragma unroll
    for (int i = 0; i < 4; ++i) {
      double dd = (double)xpr[t * 4 + i] - (double)((float)ch.h[i] + (float)cl.h[i]);
      s += dd * dd;
    }
    red[t] = s;
    __syncthreads();
    for (int st = 128; st > 0; st >>= 1) {
      if (t < st) red[t] += red[t + st];
      __syncthreads();
    }
    const double d = red[0];
    __syncthreads();
    if (d < best_d || (d == best_d && k < best_k)) { best_d = d; best_k = k; }
  }
  if (t == 0) {
    packed[n] = (unsigned long long)(uint32_t)best_k;
    bestd[n] = best_d;
  }
}

// ---- diff reduction: 64 blocks, one atomic each ----
__global__ __launch_bounds__(256) void k_diffsum(const double* __restrict__ bestd,
                                                 double* __restrict__ diffsum) {
  __shared__ double red[256];
  const int t = threadIdx.x;
  const int base = blockIdx.x * 256;
  red[t] = bestd[base + t];
  __syncthreads();
  for (int st = 128; st > 0; st >>= 1) {
    if (t < st) red[t] += red[t + st];
    __syncthreads();
  }
  if (t == 0) atomicAdd(diffsum, red[0]);
}

// ---- gather: scatter cb rows to quant; DIFF=1 also accumulates sum((q-xp)^2) ----
template <int DIFF>
__global__ __launch_bounds__(256) void k_gather2(
    const _Float16* __restrict__ cbh, const _Float16* __restrict__ cbl,
    const _Float16* __restrict__ xph, const _Float16* __restrict__ xpl,
    const unsigned long long* __restrict__ packed,
    float* __restrict__ out, double* __restrict__ diffsum,
    int n_base, int NC) {
  __shared__ float tile[64][65];
  __shared__ uint32_t sidx[64];
  __shared__ float red[256];
  const int t = threadIdx.x;
  const int n0 = blockIdx.x * 64;
  const int ng = n_base + n0;
  const int b = ng >> 10, hw0 = ng & 1023;
  const int dbeg = blockIdx.y * 256;
  if (t < 64) {
    uint32_t idx = (uint32_t)(packed[ng + t] & 0xFFFFFFFFu);
    if (idx > (KCB - 1)) idx = KCB - 1;
    sidx[t] = idx;
  }
  const int rrow = t >> 3, rcol = (t & 7) * 8;
  const int wd = t >> 4, whw = (t & 15) * 4;
  float local = 0.f;
  for (int d0 = dbeg; d0 < dbeg + 256; d0 += 64) {
    __syncthreads();
    #pragma unroll
    for (int p = 0; p < 2; ++p) {
      const int nl = p * 32 + rrow;
      const uint32_t idx = sidx[nl];
      H8 hh, ll;
      hh.u = *(const uint4*)&cbh[(size_t)idx * DCODE + d0 + rcol];
      ll.u = *(const uint4*)&cbl[(size_t)idx * DCODE + d0 + rcol];
      if (DIFF) {
        H8 ph, pl;
        ph.u = *(const uint4*)&xph[(size_t)(n0 + nl) * DCODE + d0 + rcol];
        pl.u = *(const uint4*)&xpl[(size_t)(n0 + nl) * DCODE + d0 + rcol];
        #pragma unroll
        for (int j = 0; j < 8; ++j) {
          const float q = (float)hh.h[j] + (float)ll.h[j];
          const float xv = (float)ph.h[j] + (float)pl.h[j];
          const float dd = q - xv;
          local += dd * dd;
          tile[nl][rcol + j] = q;
        }
      } else {
        #pragma unroll
        for (int j = 0; j < 8; ++j)
          tile[nl][rcol + j] = (float)hh.h[j] + (float)ll.h[j];
      }
    }
    __syncthreads();
    #pragma unroll
    for (int i = 0; i < 4; ++i) {
      const int dl = i * 16 + wd;
      float4 v;
      v.x = tile[whw + 0][dl]; v.y = tile[whw + 1][dl];
      v.z = tile[whw + 2][dl]; v.w = tile[whw + 3][dl];
      *(float4*)&out[((size_t)b * DCODE + d0 + dl) * HWSZ + hw0 + whw] = v;
    }
  }
  if (DIFF) {
    red[t] = local;
    __syncthreads();
    for (int s = 128; s > 0; s >>= 1) {
      if (t < s) red[t] += red[t + s];
      __syncthreads();
    }
    if (t == 0) atomicAdd(diffsum, (double)red[0]);
  }
}

__global__ void k_final(const unsigned long long* __restrict__ packed,
                        const double* __restrict__ diffsum,
                        float* __restrict__ out) {
  int i = blockIdx.x * 256 + threadIdx.x;
  if (i < NPOS) {
    uint32_t idx = (uint32_t)(packed[i] & 0xFFFFFFFFu);
    if (idx > (KCB - 1)) idx = KCB - 1;
    out[OUT_IDX + i] = (float)idx;
  }
  if (i == 0) out[OUT_DIFF] = (float)(*diffsum / ((double)NPOS * (double)DCODE));
}

extern "C" void kernel_launch(void* const* d_in, const int* in_sizes, int n_in,
                              void* d_out, int out_size, void* d_ws, size_t ws_size,
                              hipStream_t stream) {
  const float* x    = (const float*)d_in[0];
  const float* w    = (const float*)d_in[1];
  const float* bias = (const float*)d_in[2];
  const float* cb   = (const float*)d_in[3];
  float* out = (float*)d_out;
  char* ws = (char*)d_ws;
  unsigned long long* packed = (unsigned long long*)(ws + OFF_PACKED);
  float* cnorm = (float*)(ws + OFF_CNORM);
  double* diffsum = (double*)(ws + OFF_DIFF);
  _Float16* wh  = (_Float16*)(ws + OFF_WH);
  _Float16* wl  = (_Float16*)(ws + OFF_WL);
  _Float16* cbh = (_Float16*)(ws + OFF_CBH);
  _Float16* cbl = (_Float16*)(ws + OFF_CBL);

  // fast dyn: xh 32M | xl 32M | xph 32M | xpl 32M | xq 16M | cq 2M | bestd 128K
  const size_t need_fast = (size_t)OFF_DYN + 4u * 33554432u + 16777216u + 2097152u + 131072u;
  const bool fast = ws_size >= need_fast;

  k_init<<<64, 256, 0, stream>>>(packed, diffsum);

  if (fast) {
    char* dyn = ws + OFF_DYN;
    _Float16* xh  = (_Float16*)dyn;
    _Float16* xl  = (_Float16*)(dyn + 33554432u);
    _Float16* xph = (_Float16*)(dyn + 67108864u);
    _Float16* xpl = (_Float16*)(dyn + 100663296u);
    char* xq  = dyn + 134217728u;
    char* cq  = dyn + 150994944u;
    double* bestd = (double*)(dyn + 153092096u);
    uint16_t* dq = (uint16_t*)out;   // aliases quant region; overwritten by gather later
    k_prep_w<<<DCODE, 256, 0, stream>>>(w, wh, wl);
    k_prep_cb<<<dim3(KCB / 64, DCODE / 64), 256, 0, stream>>>(cb, cbh, cbl, cq);
    k_cnorm2<<<KCB, 256, 0, stream>>>(cbh, cbl, cnorm);
    k_prep_x<<<dim3(NPOS / 64, CIN / 64), 256, 0, stream>>>(x, xh, xl, 0);
    k_gemm_u<0, 48><<<dim3(NPOS / 256, DCODE / 256), 512, 0, stream>>>(
        xh, xl, wh, wl, bias, xph, xpl, nullptr, nullptr, xq, 0);
    k_screen_q<<<dim3(NPOS / 256, KCB / 256), 512, 0, stream>>>(xq, cq, cnorm, dq);
    k_refine<<<NPOS, 256, 0, stream>>>(dq, xph, xpl, cbh, cbl, packed, bestd);
    k_diffsum<<<64, 256, 0, stream>>>(bestd, diffsum);
    k_gather2<0><<<dim3(NPOS / 64, 4), 256, 0, stream>>>(cbh, cbl, xph, xpl, packed, out, diffsum, 0, NPOS);
  } else {
    k_prep_w<<<DCODE, 256, 0, stream>>>(w, wh, wl);
    k_prep_cb<<<dim3(KCB / 64, DCODE / 64), 256, 0, stream>>>(cb, cbh, cbl, nullptr);
    k_cnorm2<<<KCB, 256, 0, stream>>>(cbh, cbl, cnorm);
    int NC = 256;
    if      (ws_size >= OFF_DYN + (size_t)16384 * 8192) NC = 16384;
    else if (ws_size >= OFF_DYN + (size_t)8192  * 8192) NC = 8192;
    else if (ws_size >= OFF_DYN + (size_t)4096  * 8192) NC = 4096;
    else if (ws_size >= OFF_DYN + (size_t)2048  * 8192) NC = 2048;
    else if (ws_size >= OFF_DYN + (size_t)1024  * 8192) NC = 1024;
    else if (ws_size >= OFF_DYN + (size_t)512   * 8192) NC = 512;
    const int nchunks = NPOS / NC;
    char* dyn = ws + OFF_DYN;
    _Float16* xh  = (_Float16*)dyn;
    _Float16* xl  = (_Float16*)(dyn + (size_t)NC * 2048);
    _Float16* xph = (_Float16*)(dyn + (size_t)NC * 4096);
    _Float16* xpl = (_Float16*)(dyn + (size_t)NC * 6144);
    for (int c = 0; c < nchunks; ++c) {
      const int n_base = c * NC;
      k_prep_x<<<dim3(NC / 64, CIN / 64), 256, 0, stream>>>(x, xh, xl, n_base);
      k_gemm_u<0, 48><<<dim3(NC / 256, DCODE / 256), 512, 0, stream>>>(
          xh, xl, wh, wl, bias, xph, xpl, nullptr, nullptr, nullptr, 0);
      k_gemm_u<1, 48><<<dim3(NC / 256, KCB / 256), 512, 0, stream>>>(
          xph, xpl, cbh, cbl, nullptr, nullptr, nullptr, cnorm, packed, nullptr, n_base);
      k_gather2<1><<<dim3(NC / 64, 4), 256, 0, stream>>>(cbh, cbl, xph, xpl, packed, out, diffsum, n_base, NC);
    }
  }
  k_final<<<64, 256, 0, stream>>>(packed, diffsum, out);
}

// Round 20
// 348.907 us; speedup vs baseline: 1.0074x; 1.0074x over previous
//
#include <hip/hip_runtime.h>
#include <stdint.h>

// Problem constants
#define BATCH 16
#define CIN   1024
#define HWSZ  1024
#define NPOS  16384
#define DCODE 1024
#define KCB   2048

// d_out FLOAT32: [0,16777216) quant (B,D,H,W); [16777216] diff; [16777217,+16384) indices
#define OUT_QUANT 0
#define OUT_DIFF  16777216
#define OUT_IDX   16777217

// ws layout (bytes)
#define OFF_PACKED 0u            // 16384 u64 = 128 KB
#define OFF_CNORM  131072u       // 2048 f32
#define OFF_DIFF   139264u       // 1 double
#define OFF_WH     262144u       // [d][c] f16, 2 MB
#define OFF_WL     2359296u
#define OFF_CBH    4456448u      // [k][d] f16, 4 MB
#define OFF_CBL    8650752u
#define OFF_DYN    12845056u
// fast dyn: xh 32M | xl 32M | xph 32M | xpl 32M | xq 16M | cq 2M | bestd 128K
// dq u16 [16384][2048] ALIASES d_out quant region; screen->refine->gather chain.

typedef _Float16 f16x8 __attribute__((ext_vector_type(8)));
typedef float f32x4 __attribute__((ext_vector_type(4)));
typedef int i32x4 __attribute__((ext_vector_type(4)));
union H4 { _Float16 h[4]; uint2 u; };
union H8 { _Float16 h[8]; uint4 u; };
union QU { uint4 u; uint16_t v[8]; };
union B16 { char c[16]; uint4 u; };

__device__ __forceinline__ void gl_lds16(const void* g, void* l) {
  __builtin_amdgcn_global_load_lds(
      (const __attribute__((address_space(1))) uint32_t*)g,
      (__attribute__((address_space(3))) uint32_t*)l, 16, 0, 0);
}

__device__ __forceinline__ char q8(float v, float s) {
  int qi = (int)rintf(v * s);
  return (char)(qi > 127 ? 127 : (qi < -127 ? -127 : qi));
}

__global__ void k_init(unsigned long long* __restrict__ packed, double* __restrict__ diffsum) {
  int i = blockIdx.x * 256 + threadIdx.x;
  if (i < NPOS) packed[i] = 0xFFFFFFFFFFFFFFFFull;
  if (i == 0) *diffsum = 0.0;
}

__global__ __launch_bounds__(256) void k_prep_w(const float* __restrict__ w,
                                                _Float16* __restrict__ wh, _Float16* __restrict__ wl) {
  const int d = blockIdx.x;
  const int c = threadIdx.x * 4;
  float4 v = *(const float4*)&w[(size_t)d * CIN + c];
  H4 hh, ll;
  float vv[4] = {v.x, v.y, v.z, v.w};
  #pragma unroll
  for (int i = 0; i < 4; ++i) {
    _Float16 h = (_Float16)vv[i];
    hh.h[i] = h;
    ll.h[i] = (_Float16)(vv[i] - (float)h);
  }
  *(uint2*)&wh[(size_t)d * CIN + c] = hh.u;
  *(uint2*)&wl[(size_t)d * CIN + c] = ll.u;
}

// cbh/cbl [k][d] (+ optional cq i8 scale 20) from cb [d][k]
__global__ __launch_bounds__(256) void k_prep_cb(const float* __restrict__ cb,
                                                 _Float16* __restrict__ cbh, _Float16* __restrict__ cbl,
                                                 char* __restrict__ cq) {
  __shared__ float ts[64][65];
  const int t = threadIdx.x;
  const int k0 = blockIdx.x * 64, d0 = blockIdx.y * 64;
  #pragma unroll
  for (int i = 0; i < 4; ++i) {
    const int r = i * 16 + (t >> 4);
    float4 v = *(const float4*)&cb[(size_t)(d0 + r) * KCB + k0 + (t & 15) * 4];
    ts[r][(t & 15) * 4 + 0] = v.x; ts[r][(t & 15) * 4 + 1] = v.y;
    ts[r][(t & 15) * 4 + 2] = v.z; ts[r][(t & 15) * 4 + 3] = v.w;
  }
  __syncthreads();
  const int j = t >> 2;
  const int q = t & 3;
  H8 hh[2], ll[2];
  B16 qb;
  #pragma unroll
  for (int e = 0; e < 16; ++e) {
    float xv = ts[q * 16 + e][j];
    _Float16 h = (_Float16)xv;
    hh[e >> 3].h[e & 7] = h;
    ll[e >> 3].h[e & 7] = (_Float16)(xv - (float)h);
    qb.c[e] = q8(xv, 20.f);
  }
  size_t o = (size_t)(k0 + j) * DCODE + d0 + q * 16;
  *(uint4*)&cbh[o] = hh[0].u; *(uint4*)&cbh[o + 8] = hh[1].u;
  *(uint4*)&cbl[o] = ll[0].u; *(uint4*)&cbl[o + 8] = ll[1].u;
  if (cq) *(uint4*)&cq[o] = qb.u;
}

// xh/xl [nloc][c] from x[b][c][hw]
__global__ __launch_bounds__(256) void k_prep_x(const float* __restrict__ x,
                                                _Float16* __restrict__ xh, _Float16* __restrict__ xl,
                                                int n_base) {
  __shared__ float ts[64][65];
  const int t = threadIdx.x;
  const int nt0 = blockIdx.x * 64;
  const int c0 = blockIdx.y * 64;
  const int ng = n_base + nt0;
  const int b = ng >> 10, hw0 = ng & 1023;
  #pragma unroll
  for (int i = 0; i < 4; ++i) {
    const int r = i * 16 + (t >> 4);
    float4 v = *(const float4*)&x[((size_t)b * CIN + c0 + r) * HWSZ + hw0 + (t & 15) * 4];
    ts[r][(t & 15) * 4 + 0] = v.x; ts[r][(t & 15) * 4 + 1] = v.y;
    ts[r][(t & 15) * 4 + 2] = v.z; ts[r][(t & 15) * 4 + 3] = v.w;
  }
  __syncthreads();
  const int j = t >> 2;
  const int q = t & 3;
  H8 hh[2], ll[2];
  #pragma unroll
  for (int e = 0; e < 16; ++e) {
    float xv = ts[q * 16 + e][j];
    _Float16 h = (_Float16)xv;
    hh[e >> 3].h[e & 7] = h;
    ll[e >> 3].h[e & 7] = (_Float16)(xv - (float)h);
  }
  size_t o = (size_t)(nt0 + j) * CIN + c0 + q * 16;
  *(uint4*)&xh[o] = hh[0].u; *(uint4*)&xh[o + 8] = hh[1].u;
  *(uint4*)&xl[o] = ll[0].u; *(uint4*)&xl[o + 8] = ll[1].u;
}

__global__ __launch_bounds__(256) void k_cnorm2(const _Float16* __restrict__ cbh,
                                                const _Float16* __restrict__ cbl,
                                                float* __restrict__ cnorm) {
  __shared__ double rd[256];
  const int k = blockIdx.x;
  const int t = threadIdx.x;
  H4 hh, ll;
  hh.u = *(const uint2*)&cbh[(size_t)k * DCODE + t * 4];
  ll.u = *(const uint2*)&cbl[(size_t)k * DCODE + t * 4];
  double s = 0.0;
  #pragma unroll
  for (int i = 0; i < 4; ++i) {
    float v = (float)hh.h[i] + (float)ll.h[i];
    s += (double)v * v;
  }
  rd[t] = s;
  __syncthreads();
  for (int st = 128; st > 0; st >>= 1) {
    if (t < st) rd[t] += rd[t + st];
    __syncthreads();
  }
  if (t == 0) cnorm[k] = (float)rd[0];
}

// ---- Unified f16 3-product 256x256 BK=64 GEMM (r8/r15 proven schedule) ----
// __launch_bounds__(512, 1): LDS (128 KB) already limits to 1 block/CU, so the
// old min-2-blocks request only capped VGPRs at 128 and caused spills once the
// fused-xq epilogue was added (r19: 203us, FETCH +41MB). 1 lifts the cap.
// EPI 0: bias + hi/lo plane stores (swizzled repack) + optional xq i8 (scale 20).
// EPI 1: argmin -> packed (fallback).
template <int EPI, int NKTT>
__global__ __launch_bounds__(512, 1) void k_gemm_u(
    const _Float16* __restrict__ aH, const _Float16* __restrict__ aL,
    const _Float16* __restrict__ bH, const _Float16* __restrict__ bL,
    const float* __restrict__ bias,
    _Float16* __restrict__ oH, _Float16* __restrict__ oL,
    const float* __restrict__ cnorm, unsigned long long* __restrict__ packed,
    char* __restrict__ xqout, int n_base) {
  __shared__ __align__(16) _Float16 smem[65536];  // 128 KB
  const int tid = threadIdx.x;
  const int lane = tid & 63, wid = tid >> 6;
  const int wm = wid >> 2, wn = wid & 3;
  const int m0 = blockIdx.x * 256;
  const int n0 = blockIdx.y * 256;
  const int kg = lane >> 4;
  const int l7 = lane & 7;

  const int srow = lane >> 3;
  const int sg = l7 ^ srow;
  size_t srcA[4], srcB[4];
  int sdst[4];
  #pragma unroll
  for (int i = 0; i < 4; ++i) {
    const int r = i * 64 + wid * 8 + srow;
    srcA[i] = (size_t)(m0 + r) * 1024 + sg * 8;
    srcB[i] = (size_t)(n0 + r) * 1024 + sg * 8;
    sdst[i] = i * 4096 + wid * 512;
  }
  const int xrd[2] = {(kg ^ l7) * 8, ((4 + kg) ^ l7) * 8};
  int arow[8], brow[4];
  #pragma unroll
  for (int fi = 0; fi < 8; ++fi) arow[fi] = (wm * 128 + fi * 16 + (lane & 15)) * 64;
  #pragma unroll
  for (int fj = 0; fj < 4; ++fj) brow[fj] = 16384 + (wn * 64 + fj * 16 + (lane & 15)) * 64;

  auto stage = [&](int kt, int part) {
    const int tp = kt >> 4;
    const int dbase = (kt & 15) * 64;
    const int buf = (kt & 1) << 15;
    if (part == 0) {
      const _Float16* pA = (tp == 2 ? aL : aH);
      #pragma unroll
      for (int i = 0; i < 4; ++i) gl_lds16(pA + srcA[i] + dbase, smem + buf + sdst[i]);
    } else {
      const _Float16* pB = (tp == 1 ? bL : bH);
      #pragma unroll
      for (int i = 0; i < 4; ++i) gl_lds16(pB + srcB[i] + dbase, smem + buf + 16384 + sdst[i]);
    }
  };

  f32x4 acc[8][4];
  #pragma unroll
  for (int i = 0; i < 8; ++i)
    #pragma unroll
    for (int j = 0; j < 4; ++j) acc[i][j] = (f32x4){0.f, 0.f, 0.f, 0.f};

  stage(0, 0); stage(0, 1);
  asm volatile("s_waitcnt vmcnt(0)" ::: "memory");
  __builtin_amdgcn_s_barrier();
  __builtin_amdgcn_sched_barrier(0);

  for (int kt = 0; kt < NKTT; ++kt) {
    const int buf = (kt & 1) << 15;
    f16x8 bfr[4][2];
    #pragma unroll
    for (int fj = 0; fj < 4; ++fj)
      #pragma unroll
      for (int ks = 0; ks < 2; ++ks)
        bfr[fj][ks] = *(const f16x8*)&smem[buf + brow[fj] + xrd[ks]];
    #pragma unroll
    for (int q = 0; q < 4; ++q) {
      f16x8 afr[2][2];
      #pragma unroll
      for (int f2 = 0; f2 < 2; ++f2)
        #pragma unroll
        for (int ks = 0; ks < 2; ++ks)
          afr[f2][ks] = *(const f16x8*)&smem[buf + arow[q * 2 + f2] + xrd[ks]];
      if (kt < NKTT - 1) {
        if (q == 0) stage(kt + 1, 0);
        else if (q == 1) stage(kt + 1, 1);
      }
      __builtin_amdgcn_s_setprio(1);
      #pragma unroll
      for (int f2 = 0; f2 < 2; ++f2)
        #pragma unroll
        for (int fj = 0; fj < 4; ++fj)
          #pragma unroll
          for (int ks = 0; ks < 2; ++ks)
            acc[q * 2 + f2][fj] = __builtin_amdgcn_mfma_f32_16x16x32_f16(
                afr[f2][ks], bfr[fj][ks], acc[q * 2 + f2][fj], 0, 0, 0);
      __builtin_amdgcn_s_setprio(0);
      __builtin_amdgcn_sched_barrier(0);
    }
    asm volatile("s_waitcnt vmcnt(0)" ::: "memory");
    __builtin_amdgcn_s_barrier();
    __builtin_amdgcn_sched_barrier(0);
  }

  if (EPI == 1) {
    unsigned long long* su = (unsigned long long*)smem;
    float cn[4]; int kcol[4];
    #pragma unroll
    for (int fj = 0; fj < 4; ++fj) {
      kcol[fj] = n0 + wn * 64 + fj * 16 + (lane & 15);
      cn[fj] = cnorm[kcol[fj]];
    }
    #pragma unroll
    for (int fi = 0; fi < 8; ++fi) {
      #pragma unroll
      for (int r = 0; r < 4; ++r) {
        float best = 3.4e38f; int bk = 0;
        #pragma unroll
        for (int fj = 0; fj < 4; ++fj) {
          const float v = cn[fj] - 2.0f * acc[fi][fj][r];
          if (v < best) { best = v; bk = kcol[fj]; }
        }
        union { float f; uint32_t u; } cv; cv.f = best;
        uint32_t hi = cv.u ^ ((uint32_t)((int32_t)cv.u >> 31) | 0x80000000u);
        unsigned long long key = ((unsigned long long)hi << 32) | (uint32_t)bk;
        #pragma unroll
        for (int s = 1; s < 16; s <<= 1) {
          unsigned long long o = __shfl_xor(key, s, 64);
          if (o < key) key = o;
        }
        if ((lane & 15) == 0)
          su[wn * 256 + wm * 128 + fi * 16 + kg * 4 + r] = key;
      }
    }
    __syncthreads();
    if (tid < 256) {
      unsigned long long k = su[tid];
      #pragma unroll
      for (int w = 1; w < 4; ++w) {
        unsigned long long o = su[w * 256 + tid];
        if (o < k) k = o;
      }
      atomicMin(&packed[n_base + m0 + tid], k);
    }
  } else {
    // bias + hi/lo split, swizzled LDS repack; then optional xq i8
    float bi[4];
    #pragma unroll
    for (int fj = 0; fj < 4; ++fj) bi[fj] = bias[n0 + wn * 64 + fj * 16 + (lane & 15)];
    const int sw = kg << 4;
    #pragma unroll
    for (int pl = 0; pl < 2; ++pl) {
      #pragma unroll
      for (int fi = 0; fi < 8; ++fi)
        #pragma unroll
        for (int r = 0; r < 4; ++r) {
          const int pos_l = wm * 128 + fi * 16 + kg * 4 + r;
          #pragma unroll
          for (int fj = 0; fj < 4; ++fj) {
            const int d_l = wn * 64 + fj * 16 + (lane & 15);
            float v = acc[fi][fj][r] + bi[fj];
            _Float16 h = (_Float16)v;
            smem[pos_l * 256 + (d_l ^ sw)] = pl ? (_Float16)(v - (float)h) : h;
          }
        }
      __syncthreads();
      _Float16* dst = pl ? oL : oH;
      #pragma unroll
      for (int p = 0; p < 16; ++p) {
        const int row = p * 16 + (tid >> 5);
        const int lc = tid & 31;
        const int pc = lc ^ (((row >> 2) & 3) << 1);
        *(uint4*)&dst[(size_t)(m0 + row) * 1024 + n0 + lc * 8] = *(const uint4*)&smem[row * 256 + pc * 8];
      }
      __syncthreads();
    }
    if (xqout) {
      char* sm8 = (char*)smem;
      #pragma unroll
      for (int fi = 0; fi < 8; ++fi)
        #pragma unroll
        for (int r = 0; r < 4; ++r) {
          const int pos_l = wm * 128 + fi * 16 + kg * 4 + r;
          #pragma unroll
          for (int fj = 0; fj < 4; ++fj) {
            const int d_l = wn * 64 + fj * 16 + (lane & 15);
            sm8[pos_l * 256 + (d_l ^ sw)] = q8(acc[fi][fj][r] + bi[fj], 20.f);
          }
        }
      __syncthreads();
      #pragma unroll
      for (int p = 0; p < 8; ++p) {
        const int idx = p * 512 + tid;
        const int row = idx >> 4;
        const int ch = idx & 15;
        const int pch = ch ^ ((row >> 2) & 3);
        *(uint4*)&xqout[(size_t)(m0 + row) * 1024 + n0 + ch * 16] = *(const uint4*)&sm8[row * 256 + pch * 16];
      }
    }
  }
}

// ---- i8 screen GEMM (proven r15): dist quantized u16 -> dq ----
__global__ __launch_bounds__(512, 1) void k_screen_q(
    const char* __restrict__ xq, const char* __restrict__ cq,
    const float* __restrict__ cnorm, uint16_t* __restrict__ dqout) {
  __shared__ __align__(16) char smem[131072];
  const int tid = threadIdx.x;
  const int lane = tid & 63, wid = tid >> 6;
  const int wm = wid >> 2, wn = wid & 3;
  const int m0 = blockIdx.x * 256;
  const int n0 = blockIdx.y * 256;
  const int kg = lane >> 4;
  const int l7 = lane & 7;
  const int l15 = lane & 15;
  const int srow = lane >> 3;
  const int sg = l7 ^ srow;
  size_t srcA[4], srcB[4];
  int sdst[4];
  #pragma unroll
  for (int i = 0; i < 4; ++i) {
    const int r = i * 64 + wid * 8 + srow;
    srcA[i] = (size_t)(m0 + r) * 1024 + sg * 16;
    srcB[i] = (size_t)(n0 + r) * 1024 + sg * 16;
    sdst[i] = i * 8192 + wid * 1024;
  }
  const int xrd[2] = {(kg ^ l7) * 16, ((4 + kg) ^ l7) * 16};
  int arow[8], brow[4];
  #pragma unroll
  for (int fi = 0; fi < 8; ++fi) arow[fi] = (wm * 128 + fi * 16 + l15) * 128;
  #pragma unroll
  for (int fj = 0; fj < 4; ++fj) brow[fj] = 32768 + (wn * 64 + fj * 16 + l15) * 128;

  auto stage = [&](int kt, int part) {
    const int dbase = kt * 128;
    const int buf = (kt & 1) << 16;
    if (part == 0) {
      #pragma unroll
      for (int i = 0; i < 4; ++i) gl_lds16(xq + srcA[i] + dbase, smem + buf + sdst[i]);
    } else {
      #pragma unroll
      for (int i = 0; i < 4; ++i) gl_lds16(cq + srcB[i] + dbase, smem + buf + 32768 + sdst[i]);
    }
  };

  i32x4 acc[8][4];
  #pragma unroll
  for (int i = 0; i < 8; ++i)
    #pragma unroll
    for (int j = 0; j < 4; ++j) acc[i][j] = (i32x4){0, 0, 0, 0};

  stage(0, 0); stage(0, 1);
  asm volatile("s_waitcnt vmcnt(0)" ::: "memory");
  __builtin_amdgcn_s_barrier();
  __builtin_amdgcn_sched_barrier(0);

  for (int kt = 0; kt < 8; ++kt) {
    const int buf = (kt & 1) << 16;
    i32x4 bfr[4][2];
    #pragma unroll
    for (int fj = 0; fj < 4; ++fj)
      #pragma unroll
      for (int ks = 0; ks < 2; ++ks)
        bfr[fj][ks] = *(const i32x4*)&smem[buf + brow[fj] + xrd[ks]];
    #pragma unroll
    for (int q = 0; q < 4; ++q) {
      i32x4 afr[2][2];
      #pragma unroll
      for (int f2 = 0; f2 < 2; ++f2)
        #pragma unroll
        for (int ks = 0; ks < 2; ++ks)
          afr[f2][ks] = *(const i32x4*)&smem[buf + arow[q * 2 + f2] + xrd[ks]];
      if (kt < 7) {
        if (q == 0) stage(kt + 1, 0);
        else if (q == 1) stage(kt + 1, 1);
      }
      __builtin_amdgcn_s_setprio(1);
      #pragma unroll
      for (int f2 = 0; f2 < 2; ++f2)
        #pragma unroll
        for (int fj = 0; fj < 4; ++fj)
          #pragma unroll
          for (int ks = 0; ks < 2; ++ks)
            acc[q * 2 + f2][fj] = __builtin_amdgcn_mfma_i32_16x16x64_i8(
                afr[f2][ks], bfr[fj][ks], acc[q * 2 + f2][fj], 0, 0, 0);
      __builtin_amdgcn_s_setprio(0);
      __builtin_amdgcn_sched_barrier(0);
    }
    asm volatile("s_waitcnt vmcnt(0)" ::: "memory");
    __builtin_amdgcn_s_barrier();
    __builtin_amdgcn_sched_barrier(0);
  }

  uint16_t* sq = (uint16_t*)smem;
  float cn[4]; int kcolL[4];
  #pragma unroll
  for (int fj = 0; fj < 4; ++fj) {
    kcolL[fj] = wn * 64 + fj * 16 + l15;
    cn[fj] = cnorm[n0 + kcolL[fj]];
  }
  const int sw = kg << 4;
  #pragma unroll
  for (int fi = 0; fi < 8; ++fi)
    #pragma unroll
    for (int r = 0; r < 4; ++r) {
      const int pos_l = wm * 128 + fi * 16 + kg * 4 + r;
      #pragma unroll
      for (int fj = 0; fj < 4; ++fj) {
        float qf = (cn[fj] - 0.005f * (float)acc[fi][fj][r] - 512.f) * 16.f;
        uint32_t qq = qf <= 0.f ? 0u : (qf >= 65535.f ? 65535u : (uint32_t)qf);
        sq[pos_l * 256 + (kcolL[fj] ^ sw)] = (uint16_t)qq;
      }
    }
  __syncthreads();
  #pragma unroll
  for (int p = 0; p < 16; ++p) {
    const int row = p * 16 + (tid >> 5);
    const int lc = tid & 31;
    const int pc = lc ^ (((row >> 2) & 3) << 1);
    *(uint4*)&dqout[(size_t)(m0 + row) * 2048 + n0 + lc * 8] = *(const uint4*)&sq[row * 256 + pc * 8];
  }
}

// ---- refine: DETERMINISTIC candidate compaction (prefix scan, ascending k),
//      exact f64 recompute; best_d -> bestd[n] ----
__global__ __launch_bounds__(256) void k_refine(
    const uint16_t* __restrict__ dq,
    const _Float16* __restrict__ xph, const _Float16* __restrict__ xpl,
    const _Float16* __restrict__ cbh, const _Float16* __restrict__ cbl,
    unsigned long long* __restrict__ packed, double* __restrict__ bestd) {
  const int n = blockIdx.x;
  const int t = threadIdx.x;
  __shared__ float xpr[1024];
  __shared__ uint32_t smin[256];
  __shared__ double red[256];
  __shared__ int cand[256];
  __shared__ int scan[256];
  {
    H4 hh, ll;
    hh.u = *(const uint2*)&xph[(size_t)n * 1024 + t * 4];
    ll.u = *(const uint2*)&xpl[(size_t)n * 1024 + t * 4];
    #pragma unroll
    for (int i = 0; i < 4; ++i) xpr[t * 4 + i] = (float)hh.h[i] + (float)ll.h[i];
  }
  QU qv;
  qv.u = *(const uint4*)&dq[(size_t)n * 2048 + t * 8];
  uint32_t lmin = 0xFFFFFFFFu;
  #pragma unroll
  for (int j = 0; j < 8; ++j) lmin = (qv.v[j] < lmin) ? qv.v[j] : lmin;
  smin[t] = lmin;
  __syncthreads();
  for (int s = 128; s > 0; s >>= 1) {
    if (t < s && smin[t + s] < smin[t]) smin[t] = smin[t + s];
    __syncthreads();
  }
  uint32_t thr = smin[0] + 192;            // 12 dist units of i8-screen margin
  if (thr > 65535u) thr = 65535u;          // harden saturated-row corner
  // deterministic compaction: per-thread count -> inclusive scan -> ordered write
  int cnt = 0;
  #pragma unroll
  for (int j = 0; j < 8; ++j) cnt += (qv.v[j] <= thr) ? 1 : 0;
  scan[t] = cnt;
  __syncthreads();
  for (int off = 1; off < 256; off <<= 1) {
    int add = (t >= off) ? scan[t - off] : 0;
    __syncthreads();
    scan[t] += add;
    __syncthreads();
  }
  const int total = scan[255];
  int o = scan[t] - cnt;                   // exclusive prefix (ascending k order)
  #pragma unroll
  for (int j = 0; j < 8; ++j)
    if (qv.v[j] <= thr) {
      if (o < 256) cand[o] = t * 8 + j;
      ++o;
    }
  __syncthreads();
  int nc = total > 256 ? 256 : total;
  double best_d = 1e300; int best_k = 0x7FFFFFFF;
  for (int c = 0; c < nc; ++c) {
    const int k = cand[c];
    H4 ch, cl;
    ch.u = *(const uint2*)&cbh[(size_t)k * 1024 + t * 4];
    cl.u = *(const uint2*)&cbl[(size_t)k * 1024 + t * 4];
    double s = 0.0;
    #pragma unroll
    for (int i = 0; i < 4; ++i) {
      double dd = (double)xpr[t * 4 + i] - (double)((float)ch.h[i] + (float)cl.h[i]);
      s += dd * dd;
    }
    red[t] = s;
    __syncthreads();
    for (int st = 128; st > 0; st >>= 1) {
      if (t < st) red[t] += red[t + st];
      __syncthreads();
    }
    const double d = red[0];
    __syncthreads();
    if (d < best_d || (d == best_d && k < best_k)) { best_d = d; best_k = k; }
  }
  if (t == 0) {
    packed[n] = (unsigned long long)(uint32_t)best_k;
    bestd[n] = best_d;
  }
}

// ---- diff reduction: 64 blocks, one atomic each ----
__global__ __launch_bounds__(256) void k_diffsum(const double* __restrict__ bestd,
                                                 double* __restrict__ diffsum) {
  __shared__ double red[256];
  const int t = threadIdx.x;
  const int base = blockIdx.x * 256;
  red[t] = bestd[base + t];
  __syncthreads();
  for (int st = 128; st > 0; st >>= 1) {
    if (t < st) red[t] += red[t + st];
    __syncthreads();
  }
  if (t == 0) atomicAdd(diffsum, red[0]);
}

// ---- gather: scatter cb rows to quant; DIFF=1 also accumulates sum((q-xp)^2) ----
template <int DIFF>
__global__ __launch_bounds__(256) void k_gather2(
    const _Float16* __restrict__ cbh, const _Float16* __restrict__ cbl,
    const _Float16* __restrict__ xph, const _Float16* __restrict__ xpl,
    const unsigned long long* __restrict__ packed,
    float* __restrict__ out, double* __restrict__ diffsum,
    int n_base, int NC) {
  __shared__ float tile[64][65];
  __shared__ uint32_t sidx[64];
  __shared__ float red[256];
  const int t = threadIdx.x;
  const int n0 = blockIdx.x * 64;
  const int ng = n_base + n0;
  const int b = ng >> 10, hw0 = ng & 1023;
  const int dbeg = blockIdx.y * 256;
  if (t < 64) {
    uint32_t idx = (uint32_t)(packed[ng + t] & 0xFFFFFFFFu);
    if (idx > (KCB - 1)) idx = KCB - 1;
    sidx[t] = idx;
  }
  const int rrow = t >> 3, rcol = (t & 7) * 8;
  const int wd = t >> 4, whw = (t & 15) * 4;
  float local = 0.f;
  for (int d0 = dbeg; d0 < dbeg + 256; d0 += 64) {
    __syncthreads();
    #pragma unroll
    for (int p = 0; p < 2; ++p) {
      const int nl = p * 32 + rrow;
      const uint32_t idx = sidx[nl];
      H8 hh, ll;
      hh.u = *(const uint4*)&cbh[(size_t)idx * DCODE + d0 + rcol];
      ll.u = *(const uint4*)&cbl[(size_t)idx * DCODE + d0 + rcol];
      if (DIFF) {
        H8 ph, pl;
        ph.u = *(const uint4*)&xph[(size_t)(n0 + nl) * DCODE + d0 + rcol];
        pl.u = *(const uint4*)&xpl[(size_t)(n0 + nl) * DCODE + d0 + rcol];
        #pragma unroll
        for (int j = 0; j < 8; ++j) {
          const float q = (float)hh.h[j] + (float)ll.h[j];
          const float xv = (float)ph.h[j] + (float)pl.h[j];
          const float dd = q - xv;
          local += dd * dd;
          tile[nl][rcol + j] = q;
        }
      } else {
        #pragma unroll
        for (int j = 0; j < 8; ++j)
          tile[nl][rcol + j] = (float)hh.h[j] + (float)ll.h[j];
      }
    }
    __syncthreads();
    #pragma unroll
    for (int i = 0; i < 4; ++i) {
      const int dl = i * 16 + wd;
      float4 v;
      v.x = tile[whw + 0][dl]; v.y = tile[whw + 1][dl];
      v.z = tile[whw + 2][dl]; v.w = tile[whw + 3][dl];
      *(float4*)&out[((size_t)b * DCODE + d0 + dl) * HWSZ + hw0 + whw] = v;
    }
  }
  if (DIFF) {
    red[t] = local;
    __syncthreads();
    for (int s = 128; s > 0; s >>= 1) {
      if (t < s) red[t] += red[t + s];
      __syncthreads();
    }
    if (t == 0) atomicAdd(diffsum, (double)red[0]);
  }
}

__global__ void k_final(const unsigned long long* __restrict__ packed,
                        const double* __restrict__ diffsum,
                        float* __restrict__ out) {
  int i = blockIdx.x * 256 + threadIdx.x;
  if (i < NPOS) {
    uint32_t idx = (uint32_t)(packed[i] & 0xFFFFFFFFu);
    if (idx > (KCB - 1)) idx = KCB - 1;
    out[OUT_IDX + i] = (float)idx;
  }
  if (i == 0) out[OUT_DIFF] = (float)(*diffsum / ((double)NPOS * (double)DCODE));
}

extern "C" void kernel_launch(void* const* d_in, const int* in_sizes, int n_in,
                              void* d_out, int out_size, void* d_ws, size_t ws_size,
                              hipStream_t stream) {
  const float* x    = (const float*)d_in[0];
  const float* w    = (const float*)d_in[1];
  const float* bias = (const float*)d_in[2];
  const float* cb   = (const float*)d_in[3];
  float* out = (float*)d_out;
  char* ws = (char*)d_ws;
  unsigned long long* packed = (unsigned long long*)(ws + OFF_PACKED);
  float* cnorm = (float*)(ws + OFF_CNORM);
  double* diffsum = (double*)(ws + OFF_DIFF);
  _Float16* wh  = (_Float16*)(ws + OFF_WH);
  _Float16* wl  = (_Float16*)(ws + OFF_WL);
  _Float16* cbh = (_Float16*)(ws + OFF_CBH);
  _Float16* cbl = (_Float16*)(ws + OFF_CBL);

  // fast dyn: xh 32M | xl 32M | xph 32M | xpl 32M | xq 16M | cq 2M | bestd 128K
  const size_t need_fast = (size_t)OFF_DYN + 4u * 33554432u + 16777216u + 2097152u + 131072u;
  const bool fast = ws_size >= need_fast;

  k_init<<<64, 256, 0, stream>>>(packed, diffsum);

  if (fast) {
    char* dyn = ws + OFF_DYN;
    _Float16* xh  = (_Float16*)dyn;
    _Float16* xl  = (_Float16*)(dyn + 33554432u);
    _Float16* xph = (_Float16*)(dyn + 67108864u);
    _Float16* xpl = (_Float16*)(dyn + 100663296u);
    char* xq  = dyn + 134217728u;
    char* cq  = dyn + 150994944u;
    double* bestd = (double*)(dyn + 153092096u);
    uint16_t* dq = (uint16_t*)out;   // aliases quant region; overwritten by gather later
    k_prep_w<<<DCODE, 256, 0, stream>>>(w, wh, wl);
    k_prep_cb<<<dim3(KCB / 64, DCODE / 64), 256, 0, stream>>>(cb, cbh, cbl, cq);
    k_cnorm2<<<KCB, 256, 0, stream>>>(cbh, cbl, cnorm);
    k_prep_x<<<dim3(NPOS / 64, CIN / 64), 256, 0, stream>>>(x, xh, xl, 0);
    k_gemm_u<0, 48><<<dim3(NPOS / 256, DCODE / 256), 512, 0, stream>>>(
        xh, xl, wh, wl, bias, xph, xpl, nullptr, nullptr, xq, 0);
    k_screen_q<<<dim3(NPOS / 256, KCB / 256), 512, 0, stream>>>(xq, cq, cnorm, dq);
    k_refine<<<NPOS, 256, 0, stream>>>(dq, xph, xpl, cbh, cbl, packed, bestd);
    k_diffsum<<<64, 256, 0, stream>>>(bestd, diffsum);
    k_gather2<0><<<dim3(NPOS / 64, 4), 256, 0, stream>>>(cbh, cbl, xph, xpl, packed, out, diffsum, 0, NPOS);
  } else {
    k_prep_w<<<DCODE, 256, 0, stream>>>(w, wh, wl);
    k_prep_cb<<<dim3(KCB / 64, DCODE / 64), 256, 0, stream>>>(cb, cbh, cbl, nullptr);
    k_cnorm2<<<KCB, 256, 0, stream>>>(cbh, cbl, cnorm);
    int NC = 256;
    if      (ws_size >= OFF_DYN + (size_t)16384 * 8192) NC = 16384;
    else if (ws_size >= OFF_DYN + (size_t)8192  * 8192) NC = 8192;
    else if (ws_size >= OFF_DYN + (size_t)4096  * 8192) NC = 4096;
    else if (ws_size >= OFF_DYN + (size_t)2048  * 8192) NC = 2048;
    else if (ws_size >= OFF_DYN + (size_t)1024  * 8192) NC = 1024;
    else if (ws_size >= OFF_DYN + (size_t)512   * 8192) NC = 512;
    const int nchunks = NPOS / NC;
    char* dyn = ws + OFF_DYN;
    _Float16* xh  = (_Float16*)dyn;
    _Float16* xl  = (_Float16*)(dyn + (size_t)NC * 2048);
    _Float16* xph = (_Float16*)(dyn + (size_t)NC * 4096);
    _Float16* xpl = (_Float16*)(dyn + (size_t)NC * 6144);
    for (int c = 0; c < nchunks; ++c) {
      const int n_base = c * NC;
      k_prep_x<<<dim3(NC / 64, CIN / 64), 256, 0, stream>>>(x, xh, xl, n_base);
      k_gemm_u<0, 48><<<dim3(NC / 256, DCODE / 256), 512, 0, stream>>>(
          xh, xl, wh, wl, bias, xph, xpl, nullptr, nullptr, nullptr, 0);
      k_gemm_u<1, 48><<<dim3(NC / 256, KCB / 256), 512, 0, stream>>>(
          xph, xpl, cbh, cbl, nullptr, nullptr, nullptr, cnorm, packed, nullptr, n_base);
      k_gather2<1><<<dim3(NC / 64, 4), 256, 0, stream>>>(cbh, cbl, xph, xpl, packed, out, diffsum, n_base, NC);
    }
  }
  k_final<<<64, 256, 0, stream>>>(packed, diffsum, out);
}

// Round 21
// 275.843 us; speedup vs baseline: 1.2742x; 1.2649x over previous
//
#include <hip/hip_runtime.h>
#include <stdint.h>

// Problem constants
#define BATCH 16
#define CIN   1024
#define HWSZ  1024
#define NPOS  16384
#define DCODE 1024
#define KCB   2048

// d_out FLOAT32: [0,16777216) quant (B,D,H,W); [16777216] diff; [16777217,+16384) indices
#define OUT_QUANT 0
#define OUT_DIFF  16777216
#define OUT_IDX   16777217

// ws layout (bytes)
#define OFF_PACKED 0u            // 16384 u64 = 128 KB
#define OFF_CNORM  131072u       // 2048 f32
#define OFF_DIFF   139264u       // 1 double
#define OFF_WH     262144u       // [d][c] f16, 2 MB
#define OFF_WL     2359296u
#define OFF_CBH    4456448u      // [k][d] f16, 4 MB
#define OFF_CBL    8650752u
#define OFF_DYN    12845056u
// fast dyn: xh 32M | xl 32M | xph 32M | xpl 32M | xq 16M | cq 2M | bestd 128K
// dq u16 [16384][2048] ALIASES d_out quant region; screen->refine->gather chain.

typedef _Float16 f16x8 __attribute__((ext_vector_type(8)));
typedef float f32x4 __attribute__((ext_vector_type(4)));
typedef int i32x4 __attribute__((ext_vector_type(4)));
union H4 { _Float16 h[4]; uint2 u; };
union H8 { _Float16 h[8]; uint4 u; };
union QU { uint4 u; uint16_t v[8]; };
union B16 { char c[16]; uint4 u; };

__device__ __forceinline__ void gl_lds16(const void* g, void* l) {
  __builtin_amdgcn_global_load_lds(
      (const __attribute__((address_space(1))) uint32_t*)g,
      (__attribute__((address_space(3))) uint32_t*)l, 16, 0, 0);
}

__device__ __forceinline__ char q8(float v, float s) {
  int qi = (int)rintf(v * s);
  return (char)(qi > 127 ? 127 : (qi < -127 ? -127 : qi));
}

__global__ void k_init(unsigned long long* __restrict__ packed, double* __restrict__ diffsum) {
  int i = blockIdx.x * 256 + threadIdx.x;
  if (i < NPOS) packed[i] = 0xFFFFFFFFFFFFFFFFull;
  if (i == 0) *diffsum = 0.0;
}

__global__ __launch_bounds__(256) void k_prep_w(const float* __restrict__ w,
                                                _Float16* __restrict__ wh, _Float16* __restrict__ wl) {
  const int d = blockIdx.x;
  const int c = threadIdx.x * 4;
  float4 v = *(const float4*)&w[(size_t)d * CIN + c];
  H4 hh, ll;
  float vv[4] = {v.x, v.y, v.z, v.w};
  #pragma unroll
  for (int i = 0; i < 4; ++i) {
    _Float16 h = (_Float16)vv[i];
    hh.h[i] = h;
    ll.h[i] = (_Float16)(vv[i] - (float)h);
  }
  *(uint2*)&wh[(size_t)d * CIN + c] = hh.u;
  *(uint2*)&wl[(size_t)d * CIN + c] = ll.u;
}

// cbh/cbl [k][d] (+ optional cq i8 scale 20) from cb [d][k]
__global__ __launch_bounds__(256) void k_prep_cb(const float* __restrict__ cb,
                                                 _Float16* __restrict__ cbh, _Float16* __restrict__ cbl,
                                                 char* __restrict__ cq) {
  __shared__ float ts[64][65];
  const int t = threadIdx.x;
  const int k0 = blockIdx.x * 64, d0 = blockIdx.y * 64;
  #pragma unroll
  for (int i = 0; i < 4; ++i) {
    const int r = i * 16 + (t >> 4);
    float4 v = *(const float4*)&cb[(size_t)(d0 + r) * KCB + k0 + (t & 15) * 4];
    ts[r][(t & 15) * 4 + 0] = v.x; ts[r][(t & 15) * 4 + 1] = v.y;
    ts[r][(t & 15) * 4 + 2] = v.z; ts[r][(t & 15) * 4 + 3] = v.w;
  }
  __syncthreads();
  const int j = t >> 2;
  const int q = t & 3;
  H8 hh[2], ll[2];
  B16 qb;
  #pragma unroll
  for (int e = 0; e < 16; ++e) {
    float xv = ts[q * 16 + e][j];
    _Float16 h = (_Float16)xv;
    hh[e >> 3].h[e & 7] = h;
    ll[e >> 3].h[e & 7] = (_Float16)(xv - (float)h);
    qb.c[e] = q8(xv, 20.f);
  }
  size_t o = (size_t)(k0 + j) * DCODE + d0 + q * 16;
  *(uint4*)&cbh[o] = hh[0].u; *(uint4*)&cbh[o + 8] = hh[1].u;
  *(uint4*)&cbl[o] = ll[0].u; *(uint4*)&cbl[o + 8] = ll[1].u;
  if (cq) *(uint4*)&cq[o] = qb.u;
}

// xh/xl [nloc][c] from x[b][c][hw]
__global__ __launch_bounds__(256) void k_prep_x(const float* __restrict__ x,
                                                _Float16* __restrict__ xh, _Float16* __restrict__ xl,
                                                int n_base) {
  __shared__ float ts[64][65];
  const int t = threadIdx.x;
  const int nt0 = blockIdx.x * 64;
  const int c0 = blockIdx.y * 64;
  const int ng = n_base + nt0;
  const int b = ng >> 10, hw0 = ng & 1023;
  #pragma unroll
  for (int i = 0; i < 4; ++i) {
    const int r = i * 16 + (t >> 4);
    float4 v = *(const float4*)&x[((size_t)b * CIN + c0 + r) * HWSZ + hw0 + (t & 15) * 4];
    ts[r][(t & 15) * 4 + 0] = v.x; ts[r][(t & 15) * 4 + 1] = v.y;
    ts[r][(t & 15) * 4 + 2] = v.z; ts[r][(t & 15) * 4 + 3] = v.w;
  }
  __syncthreads();
  const int j = t >> 2;
  const int q = t & 3;
  H8 hh[2], ll[2];
  #pragma unroll
  for (int e = 0; e < 16; ++e) {
    float xv = ts[q * 16 + e][j];
    _Float16 h = (_Float16)xv;
    hh[e >> 3].h[e & 7] = h;
    ll[e >> 3].h[e & 7] = (_Float16)(xv - (float)h);
  }
  size_t o = (size_t)(nt0 + j) * CIN + c0 + q * 16;
  *(uint4*)&xh[o] = hh[0].u; *(uint4*)&xh[o + 8] = hh[1].u;
  *(uint4*)&xl[o] = ll[0].u; *(uint4*)&xl[o + 8] = ll[1].u;
}

// xq i8 [n][d] from xph (h-plane alone: diff << quant step 1/20) -- r15 proven
__global__ __launch_bounds__(256) void k_prep_xq(const _Float16* __restrict__ xph,
                                                 char* __restrict__ xq) {
  const size_t base = ((size_t)blockIdx.x * 256 + threadIdx.x) * 16;
  H8 a, b;
  a.u = *(const uint4*)&xph[base];
  b.u = *(const uint4*)&xph[base + 8];
  B16 qb;
  #pragma unroll
  for (int i = 0; i < 8; ++i) {
    qb.c[i] = q8((float)a.h[i], 20.f);
    qb.c[8 + i] = q8((float)b.h[i], 20.f);
  }
  *(uint4*)&xq[base] = qb.u;
}

__global__ __launch_bounds__(256) void k_cnorm2(const _Float16* __restrict__ cbh,
                                                const _Float16* __restrict__ cbl,
                                                float* __restrict__ cnorm) {
  __shared__ double rd[256];
  const int k = blockIdx.x;
  const int t = threadIdx.x;
  H4 hh, ll;
  hh.u = *(const uint2*)&cbh[(size_t)k * DCODE + t * 4];
  ll.u = *(const uint2*)&cbl[(size_t)k * DCODE + t * 4];
  double s = 0.0;
  #pragma unroll
  for (int i = 0; i < 4; ++i) {
    float v = (float)hh.h[i] + (float)ll.h[i];
    s += (double)v * v;
  }
  rd[t] = s;
  __syncthreads();
  for (int st = 128; st > 0; st >>= 1) {
    if (t < st) rd[t] += rd[t + st];
    __syncthreads();
  }
  if (t == 0) cnorm[k] = (float)rd[0];
}

// ---- Unified f16 3-product 256x256 BK=64 GEMM (r15-proven, NO xq fusion) ----
// EPI 0: bias + hi/lo plane stores (swizzled repack). EPI 1: argmin (fallback).
template <int EPI, int NKTT>
__global__ __launch_bounds__(512, 2) void k_gemm_u(
    const _Float16* __restrict__ aH, const _Float16* __restrict__ aL,
    const _Float16* __restrict__ bH, const _Float16* __restrict__ bL,
    const float* __restrict__ bias,
    _Float16* __restrict__ oH, _Float16* __restrict__ oL,
    const float* __restrict__ cnorm, unsigned long long* __restrict__ packed,
    int n_base) {
  __shared__ __align__(16) _Float16 smem[65536];  // 128 KB
  const int tid = threadIdx.x;
  const int lane = tid & 63, wid = tid >> 6;
  const int wm = wid >> 2, wn = wid & 3;
  const int m0 = blockIdx.x * 256;
  const int n0 = blockIdx.y * 256;
  const int kg = lane >> 4;
  const int l7 = lane & 7;

  const int srow = lane >> 3;
  const int sg = l7 ^ srow;
  size_t srcA[4], srcB[4];
  int sdst[4];
  #pragma unroll
  for (int i = 0; i < 4; ++i) {
    const int r = i * 64 + wid * 8 + srow;
    srcA[i] = (size_t)(m0 + r) * 1024 + sg * 8;
    srcB[i] = (size_t)(n0 + r) * 1024 + sg * 8;
    sdst[i] = i * 4096 + wid * 512;
  }
  const int xrd[2] = {(kg ^ l7) * 8, ((4 + kg) ^ l7) * 8};
  int arow[8], brow[4];
  #pragma unroll
  for (int fi = 0; fi < 8; ++fi) arow[fi] = (wm * 128 + fi * 16 + (lane & 15)) * 64;
  #pragma unroll
  for (int fj = 0; fj < 4; ++fj) brow[fj] = 16384 + (wn * 64 + fj * 16 + (lane & 15)) * 64;

  auto stage = [&](int kt, int part) {
    const int tp = kt >> 4;
    const int dbase = (kt & 15) * 64;
    const int buf = (kt & 1) << 15;
    if (part == 0) {
      const _Float16* pA = (tp == 2 ? aL : aH);
      #pragma unroll
      for (int i = 0; i < 4; ++i) gl_lds16(pA + srcA[i] + dbase, smem + buf + sdst[i]);
    } else {
      const _Float16* pB = (tp == 1 ? bL : bH);
      #pragma unroll
      for (int i = 0; i < 4; ++i) gl_lds16(pB + srcB[i] + dbase, smem + buf + 16384 + sdst[i]);
    }
  };

  f32x4 acc[8][4];
  #pragma unroll
  for (int i = 0; i < 8; ++i)
    #pragma unroll
    for (int j = 0; j < 4; ++j) acc[i][j] = (f32x4){0.f, 0.f, 0.f, 0.f};

  stage(0, 0); stage(0, 1);
  asm volatile("s_waitcnt vmcnt(0)" ::: "memory");
  __builtin_amdgcn_s_barrier();
  __builtin_amdgcn_sched_barrier(0);

  for (int kt = 0; kt < NKTT; ++kt) {
    const int buf = (kt & 1) << 15;
    f16x8 bfr[4][2];
    #pragma unroll
    for (int fj = 0; fj < 4; ++fj)
      #pragma unroll
      for (int ks = 0; ks < 2; ++ks)
        bfr[fj][ks] = *(const f16x8*)&smem[buf + brow[fj] + xrd[ks]];
    #pragma unroll
    for (int q = 0; q < 4; ++q) {
      f16x8 afr[2][2];
      #pragma unroll
      for (int f2 = 0; f2 < 2; ++f2)
        #pragma unroll
        for (int ks = 0; ks < 2; ++ks)
          afr[f2][ks] = *(const f16x8*)&smem[buf + arow[q * 2 + f2] + xrd[ks]];
      if (kt < NKTT - 1) {
        if (q == 0) stage(kt + 1, 0);
        else if (q == 1) stage(kt + 1, 1);
      }
      __builtin_amdgcn_s_setprio(1);
      #pragma unroll
      for (int f2 = 0; f2 < 2; ++f2)
        #pragma unroll
        for (int fj = 0; fj < 4; ++fj)
          #pragma unroll
          for (int ks = 0; ks < 2; ++ks)
            acc[q * 2 + f2][fj] = __builtin_amdgcn_mfma_f32_16x16x32_f16(
                afr[f2][ks], bfr[fj][ks], acc[q * 2 + f2][fj], 0, 0, 0);
      __builtin_amdgcn_s_setprio(0);
      __builtin_amdgcn_sched_barrier(0);
    }
    asm volatile("s_waitcnt vmcnt(0)" ::: "memory");
    __builtin_amdgcn_s_barrier();
    __builtin_amdgcn_sched_barrier(0);
  }

  if (EPI == 1) {
    unsigned long long* su = (unsigned long long*)smem;
    float cn[4]; int kcol[4];
    #pragma unroll
    for (int fj = 0; fj < 4; ++fj) {
      kcol[fj] = n0 + wn * 64 + fj * 16 + (lane & 15);
      cn[fj] = cnorm[kcol[fj]];
    }
    #pragma unroll
    for (int fi = 0; fi < 8; ++fi) {
      #pragma unroll
      for (int r = 0; r < 4; ++r) {
        float best = 3.4e38f; int bk = 0;
        #pragma unroll
        for (int fj = 0; fj < 4; ++fj) {
          const float v = cn[fj] - 2.0f * acc[fi][fj][r];
          if (v < best) { best = v; bk = kcol[fj]; }
        }
        union { float f; uint32_t u; } cv; cv.f = best;
        uint32_t hi = cv.u ^ ((uint32_t)((int32_t)cv.u >> 31) | 0x80000000u);
        unsigned long long key = ((unsigned long long)hi << 32) | (uint32_t)bk;
        #pragma unroll
        for (int s = 1; s < 16; s <<= 1) {
          unsigned long long o = __shfl_xor(key, s, 64);
          if (o < key) key = o;
        }
        if ((lane & 15) == 0)
          su[wn * 256 + wm * 128 + fi * 16 + kg * 4 + r] = key;
      }
    }
    __syncthreads();
    if (tid < 256) {
      unsigned long long k = su[tid];
      #pragma unroll
      for (int w = 1; w < 4; ++w) {
        unsigned long long o = su[w * 256 + tid];
        if (o < k) k = o;
      }
      atomicMin(&packed[n_base + m0 + tid], k);
    }
  } else {
    // bias + hi/lo split, swizzled LDS repack for conflict-free coalesced 16B stores
    float bi[4];
    #pragma unroll
    for (int fj = 0; fj < 4; ++fj) bi[fj] = bias[n0 + wn * 64 + fj * 16 + (lane & 15)];
    const int sw = kg << 4;
    #pragma unroll
    for (int pl = 0; pl < 2; ++pl) {
      #pragma unroll
      for (int fi = 0; fi < 8; ++fi)
        #pragma unroll
        for (int r = 0; r < 4; ++r) {
          const int pos_l = wm * 128 + fi * 16 + kg * 4 + r;
          #pragma unroll
          for (int fj = 0; fj < 4; ++fj) {
            const int d_l = wn * 64 + fj * 16 + (lane & 15);
            float v = acc[fi][fj][r] + bi[fj];
            _Float16 h = (_Float16)v;
            smem[pos_l * 256 + (d_l ^ sw)] = pl ? (_Float16)(v - (float)h) : h;
          }
        }
      __syncthreads();
      _Float16* dst = pl ? oL : oH;
      #pragma unroll
      for (int p = 0; p < 16; ++p) {
        const int row = p * 16 + (tid >> 5);
        const int lc = tid & 31;
        const int pc = lc ^ (((row >> 2) & 3) << 1);
        *(uint4*)&dst[(size_t)(m0 + row) * 1024 + n0 + lc * 8] = *(const uint4*)&smem[row * 256 + pc * 8];
      }
      __syncthreads();
    }
  }
}

// ---- i8 screen GEMM (r15 proven): dist quantized u16 -> dq ----
__global__ __launch_bounds__(512, 2) void k_screen_q(
    const char* __restrict__ xq, const char* __restrict__ cq,
    const float* __restrict__ cnorm, uint16_t* __restrict__ dqout) {
  __shared__ __align__(16) char smem[131072];
  const int tid = threadIdx.x;
  const int lane = tid & 63, wid = tid >> 6;
  const int wm = wid >> 2, wn = wid & 3;
  const int m0 = blockIdx.x * 256;
  const int n0 = blockIdx.y * 256;
  const int kg = lane >> 4;
  const int l7 = lane & 7;
  const int l15 = lane & 15;
  const int srow = lane >> 3;
  const int sg = l7 ^ srow;
  size_t srcA[4], srcB[4];
  int sdst[4];
  #pragma unroll
  for (int i = 0; i < 4; ++i) {
    const int r = i * 64 + wid * 8 + srow;
    srcA[i] = (size_t)(m0 + r) * 1024 + sg * 16;
    srcB[i] = (size_t)(n0 + r) * 1024 + sg * 16;
    sdst[i] = i * 8192 + wid * 1024;
  }
  const int xrd[2] = {(kg ^ l7) * 16, ((4 + kg) ^ l7) * 16};
  int arow[8], brow[4];
  #pragma unroll
  for (int fi = 0; fi < 8; ++fi) arow[fi] = (wm * 128 + fi * 16 + l15) * 128;
  #pragma unroll
  for (int fj = 0; fj < 4; ++fj) brow[fj] = 32768 + (wn * 64 + fj * 16 + l15) * 128;

  auto stage = [&](int kt, int part) {
    const int dbase = kt * 128;
    const int buf = (kt & 1) << 16;
    if (part == 0) {
      #pragma unroll
      for (int i = 0; i < 4; ++i) gl_lds16(xq + srcA[i] + dbase, smem + buf + sdst[i]);
    } else {
      #pragma unroll
      for (int i = 0; i < 4; ++i) gl_lds16(cq + srcB[i] + dbase, smem + buf + 32768 + sdst[i]);
    }
  };

  i32x4 acc[8][4];
  #pragma unroll
  for (int i = 0; i < 8; ++i)
    #pragma unroll
    for (int j = 0; j < 4; ++j) acc[i][j] = (i32x4){0, 0, 0, 0};

  stage(0, 0); stage(0, 1);
  asm volatile("s_waitcnt vmcnt(0)" ::: "memory");
  __builtin_amdgcn_s_barrier();
  __builtin_amdgcn_sched_barrier(0);

  for (int kt = 0; kt < 8; ++kt) {
    const int buf = (kt & 1) << 16;
    i32x4 bfr[4][2];
    #pragma unroll
    for (int fj = 0; fj < 4; ++fj)
      #pragma unroll
      for (int ks = 0; ks < 2; ++ks)
        bfr[fj][ks] = *(const i32x4*)&smem[buf + brow[fj] + xrd[ks]];
    #pragma unroll
    for (int q = 0; q < 4; ++q) {
      i32x4 afr[2][2];
      #pragma unroll
      for (int f2 = 0; f2 < 2; ++f2)
        #pragma unroll
        for (int ks = 0; ks < 2; ++ks)
          afr[f2][ks] = *(const i32x4*)&smem[buf + arow[q * 2 + f2] + xrd[ks]];
      if (kt < 7) {
        if (q == 0) stage(kt + 1, 0);
        else if (q == 1) stage(kt + 1, 1);
      }
      __builtin_amdgcn_s_setprio(1);
      #pragma unroll
      for (int f2 = 0; f2 < 2; ++f2)
        #pragma unroll
        for (int fj = 0; fj < 4; ++fj)
          #pragma unroll
          for (int ks = 0; ks < 2; ++ks)
            acc[q * 2 + f2][fj] = __builtin_amdgcn_mfma_i32_16x16x64_i8(
                afr[f2][ks], bfr[fj][ks], acc[q * 2 + f2][fj], 0, 0, 0);
      __builtin_amdgcn_s_setprio(0);
      __builtin_amdgcn_sched_barrier(0);
    }
    asm volatile("s_waitcnt vmcnt(0)" ::: "memory");
    __builtin_amdgcn_s_barrier();
    __builtin_amdgcn_sched_barrier(0);
  }

  uint16_t* sq = (uint16_t*)smem;
  float cn[4]; int kcolL[4];
  #pragma unroll
  for (int fj = 0; fj < 4; ++fj) {
    kcolL[fj] = wn * 64 + fj * 16 + l15;
    cn[fj] = cnorm[n0 + kcolL[fj]];
  }
  const int sw = kg << 4;
  #pragma unroll
  for (int fi = 0; fi < 8; ++fi)
    #pragma unroll
    for (int r = 0; r < 4; ++r) {
      const int pos_l = wm * 128 + fi * 16 + kg * 4 + r;
      #pragma unroll
      for (int fj = 0; fj < 4; ++fj) {
        float qf = (cn[fj] - 0.005f * (float)acc[fi][fj][r] - 512.f) * 16.f;
        uint32_t qq = qf <= 0.f ? 0u : (qf >= 65535.f ? 65535u : (uint32_t)qf);
        sq[pos_l * 256 + (kcolL[fj] ^ sw)] = (uint16_t)qq;
      }
    }
  __syncthreads();
  #pragma unroll
  for (int p = 0; p < 16; ++p) {
    const int row = p * 16 + (tid >> 5);
    const int lc = tid & 31;
    const int pc = lc ^ (((row >> 2) & 3) << 1);
    *(uint4*)&dqout[(size_t)(m0 + row) * 2048 + n0 + lc * 8] = *(const uint4*)&sq[row * 256 + pc * 8];
  }
}

// ---- refine: DETERMINISTIC candidate compaction (prefix scan, ascending k),
//      exact f64 recompute; best_d -> bestd[n] ----
__global__ __launch_bounds__(256) void k_refine(
    const uint16_t* __restrict__ dq,
    const _Float16* __restrict__ xph, const _Float16* __restrict__ xpl,
    const _Float16* __restrict__ cbh, const _Float16* __restrict__ cbl,
    unsigned long long* __restrict__ packed, double* __restrict__ bestd) {
  const int n = blockIdx.x;
  const int t = threadIdx.x;
  __shared__ float xpr[1024];
  __shared__ uint32_t smin[256];
  __shared__ double red[256];
  __shared__ int cand[256];
  __shared__ int scan[256];
  {
    H4 hh, ll;
    hh.u = *(const uint2*)&xph[(size_t)n * 1024 + t * 4];
    ll.u = *(const uint2*)&xpl[(size_t)n * 1024 + t * 4];
    #pragma unroll
    for (int i = 0; i < 4; ++i) xpr[t * 4 + i] = (float)hh.h[i] + (float)ll.h[i];
  }
  QU qv;
  qv.u = *(const uint4*)&dq[(size_t)n * 2048 + t * 8];
  uint32_t lmin = 0xFFFFFFFFu;
  #pragma unroll
  for (int j = 0; j < 8; ++j) lmin = (qv.v[j] < lmin) ? qv.v[j] : lmin;
  smin[t] = lmin;
  __syncthreads();
  for (int s = 128; s > 0; s >>= 1) {
    if (t < s && smin[t + s] < smin[t]) smin[t] = smin[t + s];
    __syncthreads();
  }
  uint32_t thr = smin[0] + 192;            // 12 dist units of i8-screen margin
  if (thr > 65535u) thr = 65535u;          // harden saturated-row corner
  // deterministic compaction: per-thread count -> inclusive scan -> ordered write
  int cnt = 0;
  #pragma unroll
  for (int j = 0; j < 8; ++j) cnt += (qv.v[j] <= thr) ? 1 : 0;
  scan[t] = cnt;
  __syncthreads();
  for (int off = 1; off < 256; off <<= 1) {
    int add = (t >= off) ? scan[t - off] : 0;
    __syncthreads();
    scan[t] += add;
    __syncthreads();
  }
  const int total = scan[255];
  int o = scan[t] - cnt;                   // exclusive prefix (ascending k order)
  #pragma unroll
  for (int j = 0; j < 8; ++j)
    if (qv.v[j] <= thr) {
      if (o < 256) cand[o] = t * 8 + j;
      ++o;
    }
  __syncthreads();
  int nc = total > 256 ? 256 : total;
  double best_d = 1e300; int best_k = 0x7FFFFFFF;
  for (int c = 0; c < nc; ++c) {
    const int k = cand[c];
    H4 ch, cl;
    ch.u = *(const uint2*)&cbh[(size_t)k * 1024 + t * 4];
    cl.u = *(const uint2*)&cbl[(size_t)k * 1024 + t * 4];
    double s = 0.0;
    #pragma unroll
    for (int i = 0; i < 4; ++i) {
      double dd = (double)xpr[t * 4 + i] - (double)((float)ch.h[i] + (float)cl.h[i]);
      s += dd * dd;
    }
    red[t] = s;
    __syncthreads();
    for (int st = 128; st > 0; st >>= 1) {
      if (t < st) red[t] += red[t + st];
      __syncthreads();
    }
    const double d = red[0];
    __syncthreads();
    if (d < best_d || (d == best_d && k < best_k)) { best_d = d; best_k = k; }
  }
  if (t == 0) {
    packed[n] = (unsigned long long)(uint32_t)best_k;
    bestd[n] = best_d;
  }
}

// ---- diff reduction: 64 blocks, one atomic each ----
__global__ __launch_bounds__(256) void k_diffsum(const double* __restrict__ bestd,
                                                 double* __restrict__ diffsum) {
  __shared__ double red[256];
  const int t = threadIdx.x;
  const int base = blockIdx.x * 256;
  red[t] = bestd[base + t];
  __syncthreads();
  for (int st = 128; st > 0; st >>= 1) {
    if (t < st) red[t] += red[t + st];
    __syncthreads();
  }
  if (t == 0) atomicAdd(diffsum, red[0]);
}

// ---- gather: scatter cb rows to quant; DIFF=1 also accumulates sum((q-xp)^2) ----
template <int DIFF>
__global__ __launch_bounds__(256) void k_gather2(
    const _Float16* __restrict__ cbh, const _Float16* __restrict__ cbl,
    const _Float16* __restrict__ xph, const _Float16* __restrict__ xpl,
    const unsigned long long* __restrict__ packed,
    float* __restrict__ out, double* __restrict__ diffsum,
    int n_base, int NC) {
  __shared__ float tile[64][65];
  __shared__ uint32_t sidx[64];
  __shared__ float red[256];
  const int t = threadIdx.x;
  const int n0 = blockIdx.x * 64;
  const int ng = n_base + n0;
  const int b = ng >> 10, hw0 = ng & 1023;
  const int dbeg = blockIdx.y * 256;
  if (t < 64) {
    uint32_t idx = (uint32_t)(packed[ng + t] & 0xFFFFFFFFu);
    if (idx > (KCB - 1)) idx = KCB - 1;
    sidx[t] = idx;
  }
  const int rrow = t >> 3, rcol = (t & 7) * 8;
  const int wd = t >> 4, whw = (t & 15) * 4;
  float local = 0.f;
  for (int d0 = dbeg; d0 < dbeg + 256; d0 += 64) {
    __syncthreads();
    #pragma unroll
    for (int p = 0; p < 2; ++p) {
      const int nl = p * 32 + rrow;
      const uint32_t idx = sidx[nl];
      H8 hh, ll;
      hh.u = *(const uint4*)&cbh[(size_t)idx * DCODE + d0 + rcol];
      ll.u = *(const uint4*)&cbl[(size_t)idx * DCODE + d0 + rcol];
      if (DIFF) {
        H8 ph, pl;
        ph.u = *(const uint4*)&xph[(size_t)(n0 + nl) * DCODE + d0 + rcol];
        pl.u = *(const uint4*)&xpl[(size_t)(n0 + nl) * DCODE + d0 + rcol];
        #pragma unroll
        for (int j = 0; j < 8; ++j) {
          const float q = (float)hh.h[j] + (float)ll.h[j];
          const float xv = (float)ph.h[j] + (float)pl.h[j];
          const float dd = q - xv;
          local += dd * dd;
          tile[nl][rcol + j] = q;
        }
      } else {
        #pragma unroll
        for (int j = 0; j < 8; ++j)
          tile[nl][rcol + j] = (float)hh.h[j] + (float)ll.h[j];
      }
    }
    __syncthreads();
    #pragma unroll
    for (int i = 0; i < 4; ++i) {
      const int dl = i * 16 + wd;
      float4 v;
      v.x = tile[whw + 0][dl]; v.y = tile[whw + 1][dl];
      v.z = tile[whw + 2][dl]; v.w = tile[whw + 3][dl];
      *(float4*)&out[((size_t)b * DCODE + d0 + dl) * HWSZ + hw0 + whw] = v;
    }
  }
  if (DIFF) {
    red[t] = local;
    __syncthreads();
    for (int s = 128; s > 0; s >>= 1) {
      if (t < s) red[t] += red[t + s];
      __syncthreads();
    }
    if (t == 0) atomicAdd(diffsum, (double)red[0]);
  }
}

__global__ void k_final(const unsigned long long* __restrict__ packed,
                        const double* __restrict__ diffsum,
                        float* __restrict__ out) {
  int i = blockIdx.x * 256 + threadIdx.x;
  if (i < NPOS) {
    uint32_t idx = (uint32_t)(packed[i] & 0xFFFFFFFFu);
    if (idx > (KCB - 1)) idx = KCB - 1;
    out[OUT_IDX + i] = (float)idx;
  }
  if (i == 0) out[OUT_DIFF] = (float)(*diffsum / ((double)NPOS * (double)DCODE));
}

extern "C" void kernel_launch(void* const* d_in, const int* in_sizes, int n_in,
                              void* d_out, int out_size, void* d_ws, size_t ws_size,
                              hipStream_t stream) {
  const float* x    = (const float*)d_in[0];
  const float* w    = (const float*)d_in[1];
  const float* bias = (const float*)d_in[2];
  const float* cb   = (const float*)d_in[3];
  float* out = (float*)d_out;
  char* ws = (char*)d_ws;
  unsigned long long* packed = (unsigned long long*)(ws + OFF_PACKED);
  float* cnorm = (float*)(ws + OFF_CNORM);
  double* diffsum = (double*)(ws + OFF_DIFF);
  _Float16* wh  = (_Float16*)(ws + OFF_WH);
  _Float16* wl  = (_Float16*)(ws + OFF_WL);
  _Float16* cbh = (_Float16*)(ws + OFF_CBH);
  _Float16* cbl = (_Float16*)(ws + OFF_CBL);

  // fast dyn: xh 32M | xl 32M | xph 32M | xpl 32M | xq 16M | cq 2M | bestd 128K
  const size_t need_fast = (size_t)OFF_DYN + 4u * 33554432u + 16777216u + 2097152u + 131072u;
  const bool fast = ws_size >= need_fast;

  k_init<<<64, 256, 0, stream>>>(packed, diffsum);

  if (fast) {
    char* dyn = ws + OFF_DYN;
    _Float16* xh  = (_Float16*)dyn;
    _Float16* xl  = (_Float16*)(dyn + 33554432u);
    _Float16* xph = (_Float16*)(dyn + 67108864u);
    _Float16* xpl = (_Float16*)(dyn + 100663296u);
    char* xq  = dyn + 134217728u;
    char* cq  = dyn + 150994944u;
    double* bestd = (double*)(dyn + 153092096u);
    uint16_t* dq = (uint16_t*)out;   // aliases quant region; overwritten by gather later
    k_prep_w<<<DCODE, 256, 0, stream>>>(w, wh, wl);
    k_prep_cb<<<dim3(KCB / 64, DCODE / 64), 256, 0, stream>>>(cb, cbh, cbl, cq);
    k_cnorm2<<<KCB, 256, 0, stream>>>(cbh, cbl, cnorm);
    k_prep_x<<<dim3(NPOS / 64, CIN / 64), 256, 0, stream>>>(x, xh, xl, 0);
    k_gemm_u<0, 48><<<dim3(NPOS / 256, DCODE / 256), 512, 0, stream>>>(
        xh, xl, wh, wl, bias, xph, xpl, nullptr, nullptr, 0);
    k_prep_xq<<<4096, 256, 0, stream>>>(xph, xq);
    k_screen_q<<<dim3(NPOS / 256, KCB / 256), 512, 0, stream>>>(xq, cq, cnorm, dq);
    k_refine<<<NPOS, 256, 0, stream>>>(dq, xph, xpl, cbh, cbl, packed, bestd);
    k_diffsum<<<64, 256, 0, stream>>>(bestd, diffsum);
    k_gather2<0><<<dim3(NPOS / 64, 4), 256, 0, stream>>>(cbh, cbl, xph, xpl, packed, out, diffsum, 0, NPOS);
  } else {
    k_prep_w<<<DCODE, 256, 0, stream>>>(w, wh, wl);
    k_prep_cb<<<dim3(KCB / 64, DCODE / 64), 256, 0, stream>>>(cb, cbh, cbl, nullptr);
    k_cnorm2<<<KCB, 256, 0, stream>>>(cbh, cbl, cnorm);
    int NC = 256;
    if      (ws_size >= OFF_DYN + (size_t)16384 * 8192) NC = 16384;
    else if (ws_size >= OFF_DYN + (size_t)8192  * 8192) NC = 8192;
    else if (ws_size >= OFF_DYN + (size_t)4096  * 8192) NC = 4096;
    else if (ws_size >= OFF_DYN + (size_t)2048  * 8192) NC = 2048;
    else if (ws_size >= OFF_DYN + (size_t)1024  * 8192) NC = 1024;
    else if (ws_size >= OFF_DYN + (size_t)512   * 8192) NC = 512;
    const int nchunks = NPOS / NC;
    char* dyn = ws + OFF_DYN;
    _Float16* xh  = (_Float16*)dyn;
    _Float16* xl  = (_Float16*)(dyn + (size_t)NC * 2048);
    _Float16* xph = (_Float16*)(dyn + (size_t)NC * 4096);
    _Float16* xpl = (_Float16*)(dyn + (size_t)NC * 6144);
    for (int c = 0; c < nchunks; ++c) {
      const int n_base = c * NC;
      k_prep_x<<<dim3(NC / 64, CIN / 64), 256, 0, stream>>>(x, xh, xl, n_base);
      k_gemm_u<0, 48><<<dim3(NC / 256, DCODE / 256), 512, 0, stream>>>(
          xh, xl, wh, wl, bias, xph, xpl, nullptr, nullptr, 0);
      k_gemm_u<1, 48><<<dim3(NC / 256, KCB / 256), 512, 0, stream>>>(
          xph, xpl, cbh, cbl, nullptr, nullptr, nullptr, cnorm, packed, n_base);
      k_gather2<1><<<dim3(NC / 64, 4), 256, 0, stream>>>(cbh, cbl, xph, xpl, packed, out, diffsum, n_base, NC);
    }
  }
  k_final<<<64, 256, 0, stream>>>(packed, diffsum, out);
}